// Round 1
// baseline (1719.634 us; speedup 1.0000x reference)
//
#include <hip/hip_runtime.h>
#include <cmath>

#define HEADS 4

// ---------------- GEMM: C[M,N] = A[M,K] @ B[K,N] ----------------
// MODE 0: plain.  MODE 1: C = elu(A@B + add + bias)
template<int MODE>
__global__ void gemm_kernel(const float* __restrict__ A, const float* __restrict__ B,
                            const float* __restrict__ add, const float* __restrict__ bias,
                            float* __restrict__ C, int M, int N, int K)
{
    __shared__ float As[16][65];
    __shared__ float Bs[16][65];
    int tid = threadIdx.x;
    int tx = tid & 15, ty = tid >> 4;
    int row0 = blockIdx.y * 64, col0 = blockIdx.x * 64;
    float acc[4][4];
#pragma unroll
    for (int i = 0; i < 4; i++)
#pragma unroll
        for (int j = 0; j < 4; j++) acc[i][j] = 0.f;

    for (int k0 = 0; k0 < K; k0 += 16) {
        for (int i = tid; i < 64 * 16; i += 256) {
            int r = i >> 4, c = i & 15;
            int gr = row0 + r, gc = k0 + c;
            As[c][r] = (gr < M && gc < K) ? A[(size_t)gr * K + gc] : 0.f;
        }
        for (int i = tid; i < 16 * 64; i += 256) {
            int r = i >> 6, c = i & 63;
            int gr = k0 + r, gc = col0 + c;
            Bs[r][c] = (gr < K && gc < N) ? B[(size_t)gr * N + gc] : 0.f;
        }
        __syncthreads();
#pragma unroll
        for (int kk = 0; kk < 16; kk++) {
            float a[4], b[4];
#pragma unroll
            for (int i = 0; i < 4; i++) a[i] = As[kk][ty * 4 + i];
#pragma unroll
            for (int j = 0; j < 4; j++) b[j] = Bs[kk][tx * 4 + j];
#pragma unroll
            for (int i = 0; i < 4; i++)
#pragma unroll
                for (int j = 0; j < 4; j++) acc[i][j] += a[i] * b[j];
        }
        __syncthreads();
    }
#pragma unroll
    for (int i = 0; i < 4; i++) {
        int r = row0 + ty * 4 + i;
        if (r >= M) continue;
#pragma unroll
        for (int j = 0; j < 4; j++) {
            int c = col0 + tx * 4 + j;
            if (c >= N) continue;
            float v = acc[i][j];
            if (MODE == 1) {
                v += add[(size_t)r * N + c] + bias[c];
                v = (v > 0.f) ? v : (expf(v) - 1.f);
            }
            C[(size_t)r * N + c] = v;
        }
    }
}

// ---------------- el/er: attention logit halves ----------------
// one block per node; wave h handles head h, lane d handles dim d
__global__ void el_er_kernel(const float* __restrict__ fs, const float* __restrict__ al,
                             const float* __restrict__ ar, float* __restrict__ el,
                             float* __restrict__ er, int nd, int D)
{
    int n = blockIdx.x;
    int h = threadIdx.x >> 6;
    int d = threadIdx.x & 63;
    int HD = HEADS * D;
    float v = 0.f, a = 0.f, r = 0.f;
    if (d < D) {
        v = fs[(size_t)n * HD + h * D + d];
        a = al[h * D + d];
        r = ar[h * D + d];
    }
    float pl = v * a, pr = v * r;
    for (int off = 32; off; off >>= 1) {
        pl += __shfl_down(pl, off);
        pr += __shfl_down(pr, off);
    }
    if (d == 0) {
        el[n * HEADS + h] = pl;
        if (n < nd) er[n * HEADS + h] = pr;
    }
}

// ---------------- CSR build ----------------
__global__ void zero_int_kernel(int* p, int n)
{
    for (int i = blockIdx.x * blockDim.x + threadIdx.x; i < n; i += gridDim.x * blockDim.x)
        p[i] = 0;
}

__global__ void copy_int_kernel(const int* s, int* d, int n)
{
    for (int i = blockIdx.x * blockDim.x + threadIdx.x; i < n; i += gridDim.x * blockDim.x)
        d[i] = s[i];
}

__global__ void hist_kernel(const int* __restrict__ dst, int ne, int* __restrict__ cnt)
{
    for (int i = blockIdx.x * blockDim.x + threadIdx.x; i < ne; i += gridDim.x * blockDim.x)
        atomicAdd(&cnt[dst[i]], 1);
}

// single-block exclusive scan (nd up to 50000: ~49 chunks of 1024)
__global__ void scan_kernel(const int* __restrict__ cnt, int* __restrict__ offs, int nd)
{
    __shared__ int sdata[1024];
    __shared__ int carry;
    int tid = threadIdx.x;
    if (tid == 0) carry = 0;
    __syncthreads();
    for (int base = 0; base < nd; base += 1024) {
        int i = base + tid;
        int v = (i < nd) ? cnt[i] : 0;
        sdata[tid] = v;
        __syncthreads();
        for (int off = 1; off < 1024; off <<= 1) {
            int t = (tid >= off) ? sdata[tid - off] : 0;
            __syncthreads();
            sdata[tid] += t;
            __syncthreads();
        }
        if (i < nd) offs[i] = carry + sdata[tid] - v;  // exclusive
        __syncthreads();
        if (tid == 0) carry += sdata[1023];
        __syncthreads();
    }
    if (threadIdx.x == 0) offs[nd] = carry;
}

__global__ void scatter_kernel(const int* __restrict__ src, const int* __restrict__ dst,
                               int ne, int* __restrict__ cursor, int* __restrict__ ssrc)
{
    for (int i = blockIdx.x * blockDim.x + threadIdx.x; i < ne; i += gridDim.x * blockDim.x) {
        int d = dst[i];
        int p = atomicAdd(&cursor[d], 1);
        ssrc[p] = src[i];
    }
}

// ---------------- aggregation: online softmax per (dst, head) wave ----------------
__global__ void agg_kernel(const float* __restrict__ fs, const float* __restrict__ el,
                           const float* __restrict__ er, const float* __restrict__ b,
                           const int* __restrict__ offs, const int* __restrict__ ssrc,
                           float* __restrict__ rst, int D)
{
    int n = blockIdx.x;
    int h = threadIdx.x >> 6;
    int lane = threadIdx.x & 63;
    int HD = HEADS * D;
    int s0 = offs[n], s1 = offs[n + 1];
    float er_h = er[n * HEADS + h];
    float m = -INFINITY, s = 0.f, acc = 0.f;
    for (int i = s0; i < s1; i++) {
        int sid = ssrc[i];
        float e = el[sid * HEADS + h] + er_h;
        e = (e > 0.f) ? e : 0.2f * e;
        float nm = fmaxf(m, e);
        float scale = __expf(m - nm);   // first iter: exp(-inf)=0
        float p = __expf(e - nm);
        float v = (lane < D) ? fs[(size_t)sid * HD + h * D + lane] : 0.f;
        s = s * scale + p;
        acc = acc * scale + p * v;
        m = nm;
    }
    if (lane < D) {
        float out = (s > 0.f) ? acc / s : 0.f;
        rst[(size_t)n * HD + h * D + lane] = out + b[h * D + lane];
    }
}

// ---------------- final layer: mean heads + skip + log_softmax ----------------
__global__ void final_kernel(const float* __restrict__ rst2, const float* __restrict__ h2,
                             const float* __restrict__ Ws, const float* __restrict__ bs,
                             float* __restrict__ out)
{
    const int K = 256, C = 47;
    int n = blockIdx.x;
    int c = threadIdx.x;  // 64 threads, 47 active
    float v = -INFINITY;
    if (c < C) {
        float dot = 0.f;
        for (int k = 0; k < K; k++) dot += h2[(size_t)n * K + k] * Ws[k * C + c];
        float mean = 0.f;
#pragma unroll
        for (int hh = 0; hh < HEADS; hh++) mean += rst2[(size_t)n * HEADS * C + hh * C + c];
        mean *= 0.25f;
        v = mean + dot + bs[c];
    }
    float mx = v;
    for (int off = 32; off; off >>= 1) mx = fmaxf(mx, __shfl_xor(mx, off));
    float ex = (c < C) ? __expf(v - mx) : 0.f;
    float sum = ex;
    for (int off = 32; off; off >>= 1) sum += __shfl_xor(sum, off);
    if (c < C) out[n * C + c] = v - mx - logf(sum);
}

extern "C" void kernel_launch(void* const* d_in, const int* in_sizes, int n_in,
                              void* d_out, int out_size, void* d_ws, size_t ws_size,
                              hipStream_t stream)
{
    const float* x = (const float*)d_in[0];
    const float* W[3]  = {(const float*)d_in[1],  (const float*)d_in[7],  (const float*)d_in[13]};
    const float* al[3] = {(const float*)d_in[2],  (const float*)d_in[8],  (const float*)d_in[14]};
    const float* ar[3] = {(const float*)d_in[3],  (const float*)d_in[9],  (const float*)d_in[15]};
    const float* bb[3] = {(const float*)d_in[4],  (const float*)d_in[10], (const float*)d_in[16]};
    const float* Ws[3] = {(const float*)d_in[5],  (const float*)d_in[11], (const float*)d_in[17]};
    const float* bs[3] = {(const float*)d_in[6],  (const float*)d_in[12], (const float*)d_in[18]};
    const int* srcp[3] = {(const int*)d_in[19], (const int*)d_in[21], (const int*)d_in[23]};
    const int* dstp[3] = {(const int*)d_in[20], (const int*)d_in[22], (const int*)d_in[24]};

    const int NS[3]   = {200000, 50000, 10000};
    const int ND[3]   = {50000, 10000, 2048};
    const int NEg[3]  = {800000, 400000, 100000};
    const int CIN[3]  = {128, 256, 256};
    const int DPH[3]  = {64, 64, 47};
    const int SOUT[3] = {256, 256, 47};

    float* ws   = (float*)d_ws;
    float* fs   = ws;                    // 51,200,000 floats (layer0 fs; reused)
    float* h1   = fs + 51200000;         // 12,800,000
    float* rst  = h1 + 12800000;         // 12,800,000
    float* h2   = rst + 12800000;        //  2,560,000
    float* elb  = h2 + 2560000;          //    800,000
    float* erb  = elb + 800000;          //    200,000
    int* counts = (int*)(erb + 200000);  //     50,000 ints
    int* offs   = counts + 50000;        //     50,001
    int* cursor = offs + 50001;          //     50,000
    int* ssrc   = cursor + 50000;        //    800,000

    const float* hin = x;
    float* hout[2] = {h1, h2};

    for (int l = 0; l < 3; l++) {
        int ns = NS[l], nd = ND[l], ne = NEg[l], cin = CIN[l], d = DPH[l];
        int hd = HEADS * d;

        // 1. fs = hin @ W   (fd = fs[:nd] since h_dst = h_src[:nd])
        dim3 g1((hd + 63) / 64, (ns + 63) / 64);
        gemm_kernel<0><<<g1, 256, 0, stream>>>(hin, W[l], nullptr, nullptr, fs, ns, hd, cin);

        // 2. attention logit halves
        el_er_kernel<<<ns, 256, 0, stream>>>(fs, al[l], ar[l], elb, erb, nd, d);

        // 3. CSR build (per-launch: inputs restored each call)
        zero_int_kernel<<<256, 256, 0, stream>>>(counts, nd);
        hist_kernel<<<512, 256, 0, stream>>>(dstp[l], ne, counts);
        scan_kernel<<<1, 1024, 0, stream>>>(counts, offs, nd);
        copy_int_kernel<<<256, 256, 0, stream>>>(offs, cursor, nd);
        scatter_kernel<<<512, 256, 0, stream>>>(srcp[l], dstp[l], ne, cursor, ssrc);

        // 4. per-dst online-softmax aggregation (no atomics)
        agg_kernel<<<nd, 256, 0, stream>>>(fs, elb, erb, bb[l], offs, ssrc, rst, d);

        // 5. skip connection
        if (l < 2) {
            dim3 g2((SOUT[l] + 63) / 64, (nd + 63) / 64);
            gemm_kernel<1><<<g2, 256, 0, stream>>>(hin, Ws[l], rst, bs[l], hout[l], nd, SOUT[l], cin);
            hin = hout[l];
        } else {
            final_kernel<<<nd, 64, 0, stream>>>(rst, hin, Ws[l], bs[l], (float*)d_out);
        }
    }
}

// Round 2
// 1211.111 us; speedup vs baseline: 1.4199x; 1.4199x over previous
//
#include <hip/hip_runtime.h>
#include <hip/hip_bf16.h>
#include <cmath>

#define HEADS 4
typedef __hip_bfloat16 bf16;
typedef short short8 __attribute__((ext_vector_type(8)));
typedef float floatx4 __attribute__((ext_vector_type(4)));

__device__ inline float bf2f(unsigned short u) {
    union { unsigned u; float f; } c; c.u = ((unsigned)u) << 16; return c.f;
}

// ---------------- casts ----------------
__global__ void cast4_kernel(const float4* __restrict__ in, ushort4* __restrict__ out, int n4)
{
    int i = blockIdx.x * blockDim.x + threadIdx.x;
    if (i >= n4) return;
    float4 v = in[i];
    ushort4 o;
    bf16 h;
    h = __float2bfloat16(v.x); o.x = *reinterpret_cast<unsigned short*>(&h);
    h = __float2bfloat16(v.y); o.y = *reinterpret_cast<unsigned short*>(&h);
    h = __float2bfloat16(v.z); o.z = *reinterpret_cast<unsigned short*>(&h);
    h = __float2bfloat16(v.w); o.w = *reinterpret_cast<unsigned short*>(&h);
    out[i] = o;
}

// Bt[n*K+k] = W[k*N+n], cast to bf16
__global__ void transpose_cast_kernel(const float* __restrict__ W, bf16* __restrict__ Bt, int K, int N)
{
    int i = blockIdx.x * blockDim.x + threadIdx.x;
    if (i >= K * N) return;
    int n = i / K, k = i % K;
    Bt[i] = __float2bfloat16(W[(size_t)k * N + n]);
}

// ---------------- MFMA GEMM: C[M,N] = A[M,K] @ Bt[N,K]^T ----------------
// FUSE 0: write bf16 C.  FUSE 1: v = elu(acc + add + bias); write f32 Cf and bf16 Cb.
template<int FUSE>
__global__ __launch_bounds__(256)
void gemm_mfma(const bf16* __restrict__ A, const bf16* __restrict__ Bt,
               const float* __restrict__ add, const float* __restrict__ bias,
               bf16* __restrict__ Cb, float* __restrict__ Cf,
               int M, int N, int K)
{
    const int BM = 128, BN = 128, BK = 32;
    __shared__ short As[BM * BK];
    __shared__ short Bs[BN * BK];
    int tid = threadIdx.x;
    int wave = tid >> 6, lane = tid & 63;
    int q = lane >> 4, r = lane & 15;
    int row0 = blockIdx.y * BM, col0 = blockIdx.x * BN;
    int wm = (wave >> 1) * 64, wn = (wave & 1) * 64;

    const short* As16 = (const short*)A;
    const short* Bs16 = (const short*)Bt;

    floatx4 zero = {0.f, 0.f, 0.f, 0.f};
    floatx4 acc[4][4];
#pragma unroll
    for (int i = 0; i < 4; i++)
#pragma unroll
        for (int j = 0; j < 4; j++) acc[i][j] = zero;

    for (int k0 = 0; k0 < K; k0 += BK) {
        // stage A: 128x32 bf16, each thread 2x 16B chunks
#pragma unroll
        for (int rep = 0; rep < 2; rep++) {
            int i = tid + 256 * rep;
            int rrow = i >> 2, chunk = i & 3;
            int grow = row0 + rrow;
            short8 v = {0, 0, 0, 0, 0, 0, 0, 0};
            if (grow < M) v = *(const short8*)&As16[(size_t)grow * K + k0 + chunk * 8];
            *(short8*)&As[rrow * BK + chunk * 8] = v;
        }
        // stage B
#pragma unroll
        for (int rep = 0; rep < 2; rep++) {
            int i = tid + 256 * rep;
            int rrow = i >> 2, chunk = i & 3;
            int gcol = col0 + rrow;
            short8 v = {0, 0, 0, 0, 0, 0, 0, 0};
            if (gcol < N) v = *(const short8*)&Bs16[(size_t)gcol * K + k0 + chunk * 8];
            *(short8*)&Bs[rrow * BK + chunk * 8] = v;
        }
        __syncthreads();
        short8 af[4], bfr[4];
#pragma unroll
        for (int mt = 0; mt < 4; mt++) af[mt] = *(short8*)&As[(wm + mt * 16 + r) * BK + q * 8];
#pragma unroll
        for (int nt = 0; nt < 4; nt++) bfr[nt] = *(short8*)&Bs[(wn + nt * 16 + r) * BK + q * 8];
#pragma unroll
        for (int mt = 0; mt < 4; mt++)
#pragma unroll
            for (int nt = 0; nt < 4; nt++)
                acc[mt][nt] = __builtin_amdgcn_mfma_f32_16x16x32_bf16(af[mt], bfr[nt], acc[mt][nt], 0, 0, 0);
        __syncthreads();
    }

    // epilogue: D[row=q*4+e][col=r] per 16x16 tile
#pragma unroll
    for (int mt = 0; mt < 4; mt++) {
#pragma unroll
        for (int nt = 0; nt < 4; nt++) {
            int gcol = col0 + wn + nt * 16 + r;
            if (gcol >= N) continue;
#pragma unroll
            for (int e = 0; e < 4; e++) {
                int grow = row0 + wm + mt * 16 + q * 4 + e;
                if (grow >= M) continue;
                float v = acc[mt][nt][e];
                size_t idx = (size_t)grow * N + gcol;
                if (FUSE == 1) {
                    v += add[idx] + bias[gcol];
                    v = (v > 0.f) ? v : (__expf(v) - 1.f);
                    Cf[idx] = v;
                    Cb[idx] = __float2bfloat16(v);
                } else {
                    Cb[idx] = __float2bfloat16(v);
                }
            }
        }
    }
}

// ---------------- el/er ----------------
__global__ void el_er_kernel(const bf16* __restrict__ fs, const float* __restrict__ al,
                             const float* __restrict__ ar, float* __restrict__ el,
                             float* __restrict__ er, int nd, int D)
{
    int n = blockIdx.x;
    int h = threadIdx.x >> 6;
    int d = threadIdx.x & 63;
    int HD = HEADS * D;
    float v = 0.f, a = 0.f, rr = 0.f;
    if (d < D) {
        v = __bfloat162float(fs[(size_t)n * HD + h * D + d]);
        a = al[h * D + d];
        rr = ar[h * D + d];
    }
    float pl = v * a, pr = v * rr;
    for (int off = 32; off; off >>= 1) {
        pl += __shfl_down(pl, off);
        pr += __shfl_down(pr, off);
    }
    if (d == 0) {
        el[n * HEADS + h] = pl;
        if (n < nd) er[n * HEADS + h] = pr;
    }
}

// ---------------- CSR build ----------------
__global__ void zero_int_kernel(int* p, int n)
{
    for (int i = blockIdx.x * blockDim.x + threadIdx.x; i < n; i += gridDim.x * blockDim.x)
        p[i] = 0;
}

__global__ void hist_kernel(const int* __restrict__ dst, int ne, int* __restrict__ cnt)
{
    for (int i = blockIdx.x * blockDim.x + threadIdx.x; i < ne; i += gridDim.x * blockDim.x)
        atomicAdd(&cnt[dst[i]], 1);
}

// single block, chunked: thread t owns a contiguous chunk; writes offs AND cursor
__global__ void scan_kernel(const int* __restrict__ cnt, int* __restrict__ offs,
                            int* __restrict__ cursor, int nd)
{
    __shared__ int sums[1024];
    int tid = threadIdx.x;
    int chunk = (nd + 1023) >> 10;
    int b0 = min(tid * chunk, nd), b1 = min(b0 + chunk, nd);
    int s = 0;
    for (int i = b0; i < b1; i++) s += cnt[i];
    sums[tid] = s;
    __syncthreads();
    for (int off = 1; off < 1024; off <<= 1) {
        int t = (tid >= off) ? sums[tid - off] : 0;
        __syncthreads();
        sums[tid] += t;
        __syncthreads();
    }
    int run = (tid == 0) ? 0 : sums[tid - 1];
    for (int i = b0; i < b1; i++) {
        offs[i] = run; cursor[i] = run;
        run += cnt[i];
    }
    if (tid == 0) offs[nd] = sums[1023];
}

__global__ void scatter_kernel(const int* __restrict__ src, const int* __restrict__ dst,
                               int ne, int* __restrict__ cursor, int* __restrict__ ssrc)
{
    for (int i = blockIdx.x * blockDim.x + threadIdx.x; i < ne; i += gridDim.x * blockDim.x) {
        int d = dst[i];
        int p = atomicAdd(&cursor[d], 1);
        ssrc[p] = src[i];
    }
}

// ---------------- aggregation: one wave per dst, all 4 heads ----------------
__global__ void agg_kernel(const bf16* __restrict__ fs, const float* __restrict__ el,
                           const float* __restrict__ er, const float* __restrict__ b,
                           const int* __restrict__ offs, const int* __restrict__ ssrc,
                           float* __restrict__ rst, int D, int nd)
{
    int wave = threadIdx.x >> 6, lane = threadIdx.x & 63;
    int n = blockIdx.x * 4 + wave;
    if (n >= nd) return;
    int HD = HEADS * D;
    bool act = (4 * lane) < HD;
    int h_[4];
#pragma unroll
    for (int j = 0; j < 4; j++) {
        int e = 4 * lane + j;
        h_[j] = (e < HD) ? (e / D) : 0;
    }
    float erv[4];
    {
        const float* p = &er[(size_t)n * 4];
        erv[0] = p[0]; erv[1] = p[1]; erv[2] = p[2]; erv[3] = p[3];
    }
    float m_[4], s_[4], a_[4];
#pragma unroll
    for (int j = 0; j < 4; j++) { m_[j] = -INFINITY; s_[j] = 0.f; a_[j] = 0.f; }

    int s0 = offs[n], s1 = offs[n + 1];
    const unsigned short* fsu = (const unsigned short*)fs;
    for (int i = s0; i < s1; i++) {
        int sid = ssrc[i];
        float ev[4];
        {
            const float* p = &el[(size_t)sid * 4];
#pragma unroll
            for (int h = 0; h < 4; h++) {
                float e = p[h] + erv[h];
                ev[h] = (e > 0.f) ? e : 0.2f * e;
            }
        }
        ushort4 f = {0, 0, 0, 0};
        if (act) f = *(const ushort4*)&fsu[(size_t)sid * HD + 4 * lane];
        unsigned short fa[4] = {f.x, f.y, f.z, f.w};
#pragma unroll
        for (int j = 0; j < 4; j++) {
            int h = h_[j];
            float e = (h == 0) ? ev[0] : (h == 1) ? ev[1] : (h == 2) ? ev[2] : ev[3];
            float nm = fmaxf(m_[j], e);
            float sc = __expf(m_[j] - nm);
            float p = __expf(e - nm);
            s_[j] = s_[j] * sc + p;
            a_[j] = a_[j] * sc + p * bf2f(fa[j]);
            m_[j] = nm;
        }
    }
    if (act) {
#pragma unroll
        for (int j = 0; j < 4; j++) {
            int e4 = 4 * lane + j;
            float o = (s_[j] > 0.f) ? a_[j] / s_[j] : 0.f;
            rst[(size_t)n * HD + e4] = o + b[e4];
        }
    }
}

// ---------------- final layer ----------------
__global__ void final_kernel(const float* __restrict__ rst2, const float* __restrict__ h2,
                             const float* __restrict__ Ws, const float* __restrict__ bs,
                             float* __restrict__ out)
{
    const int K = 256, C = 47;
    int n = blockIdx.x;
    int c = threadIdx.x;
    float v = -INFINITY;
    if (c < C) {
        float dot = 0.f;
        for (int k = 0; k < K; k++) dot += h2[(size_t)n * K + k] * Ws[k * C + c];
        float mean = 0.f;
#pragma unroll
        for (int hh = 0; hh < HEADS; hh++) mean += rst2[(size_t)n * HEADS * C + hh * C + c];
        mean *= 0.25f;
        v = mean + dot + bs[c];
    }
    float mx = v;
    for (int off = 32; off; off >>= 1) mx = fmaxf(mx, __shfl_xor(mx, off));
    float ex = (c < C) ? __expf(v - mx) : 0.f;
    float sum = ex;
    for (int off = 32; off; off >>= 1) sum += __shfl_xor(sum, off);
    if (c < C) out[n * C + c] = v - mx - logf(sum);
}

extern "C" void kernel_launch(void* const* d_in, const int* in_sizes, int n_in,
                              void* d_out, int out_size, void* d_ws, size_t ws_size,
                              hipStream_t stream)
{
    const float* x = (const float*)d_in[0];
    const float* W[3]  = {(const float*)d_in[1],  (const float*)d_in[7],  (const float*)d_in[13]};
    const float* al[3] = {(const float*)d_in[2],  (const float*)d_in[8],  (const float*)d_in[14]};
    const float* ar[3] = {(const float*)d_in[3],  (const float*)d_in[9],  (const float*)d_in[15]};
    const float* bb[3] = {(const float*)d_in[4],  (const float*)d_in[10], (const float*)d_in[16]};
    const float* Ws[3] = {(const float*)d_in[5],  (const float*)d_in[11], (const float*)d_in[17]};
    const float* bs[3] = {(const float*)d_in[6],  (const float*)d_in[12], (const float*)d_in[18]};
    const int* srcp[3] = {(const int*)d_in[19], (const int*)d_in[21], (const int*)d_in[23]};
    const int* dstp[3] = {(const int*)d_in[20], (const int*)d_in[22], (const int*)d_in[24]};

    const int NS[3]  = {200000, 50000, 10000};
    const int ND[3]  = {50000, 10000, 2048};
    const int NEg[3] = {800000, 400000, 100000};
    const int CIN[3] = {128, 256, 256};
    const int DPH[3] = {64, 64, 47};

    char* p = (char*)d_ws;
    auto alloc = [&](size_t bytes) -> void* {
        void* r = (void*)p;
        p += (bytes + 255) & ~(size_t)255;
        return r;
    };
    bf16*  xb   = (bf16*)alloc((size_t)200000 * 128 * 2);
    bf16*  fsb  = (bf16*)alloc((size_t)200000 * 256 * 2);
    float* h1f  = (float*)alloc((size_t)50000 * 256 * 4);
    bf16*  h1b  = (bf16*)alloc((size_t)50000 * 256 * 2);
    float* h2f  = (float*)alloc((size_t)10000 * 256 * 4);
    bf16*  h2b  = (bf16*)alloc((size_t)10000 * 256 * 2);
    float* rst  = (float*)alloc((size_t)50000 * 256 * 4);
    float* elb  = (float*)alloc((size_t)200000 * 4 * 4);
    float* erb  = (float*)alloc((size_t)50000 * 4 * 4);
    bf16*  Wt[3];  bf16* Wst[2];
    Wt[0]  = (bf16*)alloc(128 * 256 * 2);
    Wt[1]  = (bf16*)alloc(256 * 256 * 2);
    Wt[2]  = (bf16*)alloc(256 * 188 * 2);
    Wst[0] = (bf16*)alloc(128 * 256 * 2);
    Wst[1] = (bf16*)alloc(256 * 256 * 2);
    int* counts = (int*)alloc(50000 * 4);
    int* offs   = (int*)alloc(50001 * 4);
    int* cursor = (int*)alloc(50000 * 4);
    int* ssrc   = (int*)alloc(800000 * 4);

    // cast x -> bf16
    {
        int n4 = 200000 * 128 / 4;
        cast4_kernel<<<(n4 + 255) / 256, 256, 0, stream>>>((const float4*)x, (ushort4*)xb, n4);
    }
    // transpose+cast weights
    {
        int sz;
        sz = 128 * 256; transpose_cast_kernel<<<(sz + 255) / 256, 256, 0, stream>>>(W[0],  Wt[0],  128, 256);
        sz = 256 * 256; transpose_cast_kernel<<<(sz + 255) / 256, 256, 0, stream>>>(W[1],  Wt[1],  256, 256);
        sz = 256 * 188; transpose_cast_kernel<<<(sz + 255) / 256, 256, 0, stream>>>(W[2],  Wt[2],  256, 188);
        sz = 128 * 256; transpose_cast_kernel<<<(sz + 255) / 256, 256, 0, stream>>>(Ws[0], Wst[0], 128, 256);
        sz = 256 * 256; transpose_cast_kernel<<<(sz + 255) / 256, 256, 0, stream>>>(Ws[1], Wst[1], 256, 256);
    }

    const bf16* hin_b = xb;
    float* hf[2] = {h1f, h2f};
    bf16*  hb[2] = {h1b, h2b};

    for (int l = 0; l < 3; l++) {
        int ns = NS[l], nd = ND[l], ne = NEg[l], cin = CIN[l], d = DPH[l];
        int hd = HEADS * d;

        // 1. fs = hin @ W (bf16 MFMA), fd = fs[:nd]
        dim3 g1((hd + 127) / 128, (ns + 127) / 128);
        gemm_mfma<0><<<g1, 256, 0, stream>>>(hin_b, Wt[l], nullptr, nullptr, fsb, nullptr, ns, hd, cin);

        // 2. attention logit halves
        el_er_kernel<<<ns, 256, 0, stream>>>(fsb, al[l], ar[l], elb, erb, nd, d);

        // 3. CSR build
        zero_int_kernel<<<256, 256, 0, stream>>>(counts, nd);
        hist_kernel<<<512, 256, 0, stream>>>(dstp[l], ne, counts);
        scan_kernel<<<1, 1024, 0, stream>>>(counts, offs, cursor, nd);
        scatter_kernel<<<512, 256, 0, stream>>>(srcp[l], dstp[l], ne, cursor, ssrc);

        // 4. per-dst online-softmax aggregation (one wave per dst, 4 heads)
        agg_kernel<<<(nd + 3) / 4, 256, 0, stream>>>(fsb, elb, erb, bb[l], offs, ssrc, rst, d, nd);

        // 5. skip connection
        if (l < 2) {
            dim3 g2((256 + 127) / 128, (nd + 127) / 128);
            gemm_mfma<1><<<g2, 256, 0, stream>>>(hin_b, Wst[l], rst, bs[l], hb[l], hf[l], nd, 256, cin);
            hin_b = hb[l];
        } else {
            final_kernel<<<nd, 64, 0, stream>>>(rst, h2f, Ws[l], bs[l], (float*)d_out);
        }
    }
}

// Round 3
// 1130.917 us; speedup vs baseline: 1.5206x; 1.0709x over previous
//
#include <hip/hip_runtime.h>
#include <hip/hip_bf16.h>
#include <cmath>

#define HEADS 4
typedef __hip_bfloat16 bf16;
typedef short short8 __attribute__((ext_vector_type(8)));
typedef float floatx4 __attribute__((ext_vector_type(4)));

__device__ inline float bf2f(unsigned short u) {
    union { unsigned u; float f; } c; c.u = ((unsigned)u) << 16; return c.f;
}

// ---------------- casts ----------------
__global__ void cast4_kernel(const float4* __restrict__ in, ushort4* __restrict__ out, int n4)
{
    int i = blockIdx.x * blockDim.x + threadIdx.x;
    if (i >= n4) return;
    float4 v = in[i];
    ushort4 o;
    bf16 h;
    h = __float2bfloat16(v.x); o.x = *reinterpret_cast<unsigned short*>(&h);
    h = __float2bfloat16(v.y); o.y = *reinterpret_cast<unsigned short*>(&h);
    h = __float2bfloat16(v.z); o.z = *reinterpret_cast<unsigned short*>(&h);
    h = __float2bfloat16(v.w); o.w = *reinterpret_cast<unsigned short*>(&h);
    out[i] = o;
}

// Bt[n*K+k] = W[k*N+n], cast to bf16
__global__ void transpose_cast_kernel(const float* __restrict__ W, bf16* __restrict__ Bt, int K, int N)
{
    int i = blockIdx.x * blockDim.x + threadIdx.x;
    if (i >= K * N) return;
    int n = i / K, k = i % K;
    Bt[i] = __float2bfloat16(W[(size_t)k * N + n]);
}

// ---------------- MFMA GEMM: C[M,N] = A[M,K] @ Bt[N,K]^T ----------------
template<int FUSE>
__global__ __launch_bounds__(256)
void gemm_mfma(const bf16* __restrict__ A, const bf16* __restrict__ Bt,
               const float* __restrict__ add, const float* __restrict__ bias,
               bf16* __restrict__ Cb, float* __restrict__ Cf,
               int M, int N, int K)
{
    const int BM = 128, BN = 128, BK = 32;
    __shared__ short As[BM * BK];
    __shared__ short Bs[BN * BK];
    int tid = threadIdx.x;
    int wave = tid >> 6, lane = tid & 63;
    int q = lane >> 4, r = lane & 15;
    int row0 = blockIdx.y * BM, col0 = blockIdx.x * BN;
    int wm = (wave >> 1) * 64, wn = (wave & 1) * 64;

    const short* As16 = (const short*)A;
    const short* Bs16 = (const short*)Bt;

    floatx4 zero = {0.f, 0.f, 0.f, 0.f};
    floatx4 acc[4][4];
#pragma unroll
    for (int i = 0; i < 4; i++)
#pragma unroll
        for (int j = 0; j < 4; j++) acc[i][j] = zero;

    for (int k0 = 0; k0 < K; k0 += BK) {
#pragma unroll
        for (int rep = 0; rep < 2; rep++) {
            int i = tid + 256 * rep;
            int rrow = i >> 2, chunk = i & 3;
            int grow = row0 + rrow;
            short8 v = {0, 0, 0, 0, 0, 0, 0, 0};
            if (grow < M) v = *(const short8*)&As16[(size_t)grow * K + k0 + chunk * 8];
            *(short8*)&As[rrow * BK + chunk * 8] = v;
        }
#pragma unroll
        for (int rep = 0; rep < 2; rep++) {
            int i = tid + 256 * rep;
            int rrow = i >> 2, chunk = i & 3;
            int gcol = col0 + rrow;
            short8 v = {0, 0, 0, 0, 0, 0, 0, 0};
            if (gcol < N) v = *(const short8*)&Bs16[(size_t)gcol * K + k0 + chunk * 8];
            *(short8*)&Bs[rrow * BK + chunk * 8] = v;
        }
        __syncthreads();
        short8 af[4], bfr[4];
#pragma unroll
        for (int mt = 0; mt < 4; mt++) af[mt] = *(short8*)&As[(wm + mt * 16 + r) * BK + q * 8];
#pragma unroll
        for (int nt = 0; nt < 4; nt++) bfr[nt] = *(short8*)&Bs[(wn + nt * 16 + r) * BK + q * 8];
#pragma unroll
        for (int mt = 0; mt < 4; mt++)
#pragma unroll
            for (int nt = 0; nt < 4; nt++)
                acc[mt][nt] = __builtin_amdgcn_mfma_f32_16x16x32_bf16(af[mt], bfr[nt], acc[mt][nt], 0, 0, 0);
        __syncthreads();
    }

#pragma unroll
    for (int mt = 0; mt < 4; mt++) {
#pragma unroll
        for (int nt = 0; nt < 4; nt++) {
            int gcol = col0 + wn + nt * 16 + r;
            if (gcol >= N) continue;
#pragma unroll
            for (int e = 0; e < 4; e++) {
                int grow = row0 + wm + mt * 16 + q * 4 + e;
                if (grow >= M) continue;
                float v = acc[mt][nt][e];
                size_t idx = (size_t)grow * N + gcol;
                if (FUSE == 1) {
                    v += add[idx] + bias[gcol];
                    v = (v > 0.f) ? v : (__expf(v) - 1.f);
                    Cf[idx] = v;
                    Cb[idx] = __float2bfloat16(v);
                } else {
                    Cb[idx] = __float2bfloat16(v);
                }
            }
        }
    }
}

// ---------------- el/er ----------------
__global__ void el_er_kernel(const bf16* __restrict__ fs, const float* __restrict__ al,
                             const float* __restrict__ ar, float* __restrict__ el,
                             float* __restrict__ er, int nd, int D)
{
    int n = blockIdx.x;
    int h = threadIdx.x >> 6;
    int d = threadIdx.x & 63;
    int HD = HEADS * D;
    float v = 0.f, a = 0.f, rr = 0.f;
    if (d < D) {
        v = __bfloat162float(fs[(size_t)n * HD + h * D + d]);
        a = al[h * D + d];
        rr = ar[h * D + d];
    }
    float pl = v * a, pr = v * rr;
    for (int off = 32; off; off >>= 1) {
        pl += __shfl_down(pl, off);
        pr += __shfl_down(pr, off);
    }
    if (d == 0) {
        el[n * HEADS + h] = pl;
        if (n < nd) er[n * HEADS + h] = pr;
    }
}

// ---------------- CSR build ----------------
__global__ void zero_int_kernel(int* p, int n)
{
    for (int i = blockIdx.x * blockDim.x + threadIdx.x; i < n; i += gridDim.x * blockDim.x)
        p[i] = 0;
}

__global__ void hist_kernel(const int* __restrict__ dst, int ne, int* __restrict__ cnt)
{
    for (int i = blockIdx.x * blockDim.x + threadIdx.x; i < ne; i += gridDim.x * blockDim.x)
        atomicAdd(&cnt[dst[i]], 1);
}

__global__ void scan_kernel(const int* __restrict__ cnt, int* __restrict__ offs,
                            int* __restrict__ cursor, int nd)
{
    __shared__ int sums[1024];
    int tid = threadIdx.x;
    int chunk = (nd + 1023) >> 10;
    int b0 = min(tid * chunk, nd), b1 = min(b0 + chunk, nd);
    int s = 0;
    for (int i = b0; i < b1; i++) s += cnt[i];
    sums[tid] = s;
    __syncthreads();
    for (int off = 1; off < 1024; off <<= 1) {
        int t = (tid >= off) ? sums[tid - off] : 0;
        __syncthreads();
        sums[tid] += t;
        __syncthreads();
    }
    int run = (tid == 0) ? 0 : sums[tid - 1];
    for (int i = b0; i < b1; i++) {
        offs[i] = run; cursor[i] = run;
        run += cnt[i];
    }
    if (tid == 0) offs[nd] = sums[1023];
}

__global__ void scatter_kernel(const int* __restrict__ src, const int* __restrict__ dst,
                               int ne, int* __restrict__ cursor, int* __restrict__ ssrc)
{
    for (int i = blockIdx.x * blockDim.x + threadIdx.x; i < ne; i += gridDim.x * blockDim.x) {
        int d = dst[i];
        int p = atomicAdd(&cursor[d], 1);
        ssrc[p] = src[i];
    }
}

// ---------------- attention: per-dst softmax over edges, writes normalized alpha ----------------
// one wave per dst; lanes parallel over edges
__global__ void attn_kernel(const float* __restrict__ el, const float* __restrict__ er,
                            const int* __restrict__ offs, const int* __restrict__ ssrc,
                            float4* __restrict__ alpha, int nd)
{
    int wave = threadIdx.x >> 6, lane = threadIdx.x & 63;
    int n = blockIdx.x * 4 + wave;
    if (n >= nd) return;
    int s0 = offs[n], s1 = offs[n + 1];
    float4 erv = *(const float4*)&er[(size_t)n * 4];

    float m0 = -INFINITY, m1 = -INFINITY, m2 = -INFINITY, m3 = -INFINITY;
    for (int i = s0 + lane; i < s1; i += 64) {
        int sid = ssrc[i];
        float4 ev = *(const float4*)&el[(size_t)sid * 4];
        float e0 = ev.x + erv.x; e0 = (e0 > 0.f) ? e0 : 0.2f * e0;
        float e1 = ev.y + erv.y; e1 = (e1 > 0.f) ? e1 : 0.2f * e1;
        float e2 = ev.z + erv.z; e2 = (e2 > 0.f) ? e2 : 0.2f * e2;
        float e3 = ev.w + erv.w; e3 = (e3 > 0.f) ? e3 : 0.2f * e3;
        alpha[i] = make_float4(e0, e1, e2, e3);
        m0 = fmaxf(m0, e0); m1 = fmaxf(m1, e1); m2 = fmaxf(m2, e2); m3 = fmaxf(m3, e3);
    }
#pragma unroll
    for (int off = 32; off; off >>= 1) {
        m0 = fmaxf(m0, __shfl_xor(m0, off));
        m1 = fmaxf(m1, __shfl_xor(m1, off));
        m2 = fmaxf(m2, __shfl_xor(m2, off));
        m3 = fmaxf(m3, __shfl_xor(m3, off));
    }
    float t0 = 0.f, t1 = 0.f, t2 = 0.f, t3 = 0.f;
    for (int i = s0 + lane; i < s1; i += 64) {
        float4 e = alpha[i];
        float p0 = __expf(e.x - m0), p1 = __expf(e.y - m1);
        float p2 = __expf(e.z - m2), p3 = __expf(e.w - m3);
        alpha[i] = make_float4(p0, p1, p2, p3);
        t0 += p0; t1 += p1; t2 += p2; t3 += p3;
    }
#pragma unroll
    for (int off = 32; off; off >>= 1) {
        t0 += __shfl_xor(t0, off);
        t1 += __shfl_xor(t1, off);
        t2 += __shfl_xor(t2, off);
        t3 += __shfl_xor(t3, off);
    }
    float r0 = (t0 > 0.f) ? 1.f / t0 : 0.f;
    float r1 = (t1 > 0.f) ? 1.f / t1 : 0.f;
    float r2 = (t2 > 0.f) ? 1.f / t2 : 0.f;
    float r3 = (t3 > 0.f) ? 1.f / t3 : 0.f;
    for (int i = s0 + lane; i < s1; i += 64) {
        float4 pv = alpha[i];
        alpha[i] = make_float4(pv.x * r0, pv.y * r1, pv.z * r2, pv.w * r3);
    }
}

// ---------------- aggregation: pure gather + FMA (alpha pre-normalized) ----------------
__global__ void agg_kernel(const bf16* __restrict__ fs, const float4* __restrict__ alpha,
                           const float* __restrict__ b,
                           const int* __restrict__ offs, const int* __restrict__ ssrc,
                           float* __restrict__ rst, int D, int nd)
{
    int wave = threadIdx.x >> 6, lane = threadIdx.x & 63;
    int n = blockIdx.x * 4 + wave;
    if (n >= nd) return;
    int HD = HEADS * D;
    bool act = (4 * lane) < HD;
    int h_[4];
#pragma unroll
    for (int j = 0; j < 4; j++) {
        int e = 4 * lane + j;
        h_[j] = (e < HD) ? (e / D) : 0;
    }
    float acc[4] = {0.f, 0.f, 0.f, 0.f};
    int s0 = offs[n], s1 = offs[n + 1];
    const unsigned short* fsu = (const unsigned short*)fs;
    for (int i = s0; i < s1; i++) {
        int sid = ssrc[i];
        float4 av = alpha[i];
        float a_[4] = {av.x, av.y, av.z, av.w};
        ushort4 f = {0, 0, 0, 0};
        if (act) f = *(const ushort4*)&fsu[(size_t)sid * HD + 4 * lane];
        unsigned short fa[4] = {f.x, f.y, f.z, f.w};
#pragma unroll
        for (int j = 0; j < 4; j++)
            acc[j] += a_[h_[j]] * bf2f(fa[j]);
    }
    if (act) {
#pragma unroll
        for (int j = 0; j < 4; j++) {
            int e4 = 4 * lane + j;
            rst[(size_t)n * HD + e4] = acc[j] + b[e4];
        }
    }
}

// ---------------- final layer ----------------
__global__ void final_kernel(const float* __restrict__ rst2, const float* __restrict__ h2,
                             const float* __restrict__ Ws, const float* __restrict__ bs,
                             float* __restrict__ out)
{
    const int K = 256, C = 47;
    int n = blockIdx.x;
    int c = threadIdx.x;
    float v = -INFINITY;
    if (c < C) {
        float dot = 0.f;
        for (int k = 0; k < K; k++) dot += h2[(size_t)n * K + k] * Ws[k * C + c];
        float mean = 0.f;
#pragma unroll
        for (int hh = 0; hh < HEADS; hh++) mean += rst2[(size_t)n * HEADS * C + hh * C + c];
        mean *= 0.25f;
        v = mean + dot + bs[c];
    }
    float mx = v;
    for (int off = 32; off; off >>= 1) mx = fmaxf(mx, __shfl_xor(mx, off));
    float ex = (c < C) ? __expf(v - mx) : 0.f;
    float sum = ex;
    for (int off = 32; off; off >>= 1) sum += __shfl_xor(sum, off);
    if (c < C) out[n * C + c] = v - mx - logf(sum);
}

extern "C" void kernel_launch(void* const* d_in, const int* in_sizes, int n_in,
                              void* d_out, int out_size, void* d_ws, size_t ws_size,
                              hipStream_t stream)
{
    const float* x = (const float*)d_in[0];
    const float* W[3]  = {(const float*)d_in[1],  (const float*)d_in[7],  (const float*)d_in[13]};
    const float* al[3] = {(const float*)d_in[2],  (const float*)d_in[8],  (const float*)d_in[14]};
    const float* ar[3] = {(const float*)d_in[3],  (const float*)d_in[9],  (const float*)d_in[15]};
    const float* bb[3] = {(const float*)d_in[4],  (const float*)d_in[10], (const float*)d_in[16]};
    const float* Ws[3] = {(const float*)d_in[5],  (const float*)d_in[11], (const float*)d_in[17]};
    const float* bs[3] = {(const float*)d_in[6],  (const float*)d_in[12], (const float*)d_in[18]};
    const int* srcp[3] = {(const int*)d_in[19], (const int*)d_in[21], (const int*)d_in[23]};
    const int* dstp[3] = {(const int*)d_in[20], (const int*)d_in[22], (const int*)d_in[24]};

    const int NS[3]  = {200000, 50000, 10000};
    const int ND[3]  = {50000, 10000, 2048};
    const int NEg[3] = {800000, 400000, 100000};
    const int CIN[3] = {128, 256, 256};
    const int DPH[3] = {64, 64, 47};

    char* p = (char*)d_ws;
    auto alloc = [&](size_t bytes) -> void* {
        void* r = (void*)p;
        p += (bytes + 255) & ~(size_t)255;
        return r;
    };
    bf16*  xb   = (bf16*)alloc((size_t)200000 * 128 * 2);
    bf16*  fsb  = (bf16*)alloc((size_t)200000 * 256 * 2);
    float* h1f  = (float*)alloc((size_t)50000 * 256 * 4);
    bf16*  h1b  = (bf16*)alloc((size_t)50000 * 256 * 2);
    float* h2f  = (float*)alloc((size_t)10000 * 256 * 4);
    bf16*  h2b  = (bf16*)alloc((size_t)10000 * 256 * 2);
    float* rst  = (float*)alloc((size_t)50000 * 256 * 4);
    float* elb  = (float*)alloc((size_t)200000 * 4 * 4);
    float* erb  = (float*)alloc((size_t)50000 * 4 * 4);
    float4* alpha = (float4*)alloc((size_t)800000 * 16);
    bf16*  Wt[3];  bf16* Wst[2];
    Wt[0]  = (bf16*)alloc(128 * 256 * 2);
    Wt[1]  = (bf16*)alloc(256 * 256 * 2);
    Wt[2]  = (bf16*)alloc(256 * 188 * 2);
    Wst[0] = (bf16*)alloc(128 * 256 * 2);
    Wst[1] = (bf16*)alloc(256 * 256 * 2);
    int* counts = (int*)alloc(50000 * 4);
    int* offs   = (int*)alloc(50001 * 4);
    int* cursor = (int*)alloc(50000 * 4);
    int* ssrc   = (int*)alloc(800000 * 4);

    {
        int n4 = 200000 * 128 / 4;
        cast4_kernel<<<(n4 + 255) / 256, 256, 0, stream>>>((const float4*)x, (ushort4*)xb, n4);
    }
    {
        int sz;
        sz = 128 * 256; transpose_cast_kernel<<<(sz + 255) / 256, 256, 0, stream>>>(W[0],  Wt[0],  128, 256);
        sz = 256 * 256; transpose_cast_kernel<<<(sz + 255) / 256, 256, 0, stream>>>(W[1],  Wt[1],  256, 256);
        sz = 256 * 188; transpose_cast_kernel<<<(sz + 255) / 256, 256, 0, stream>>>(W[2],  Wt[2],  256, 188);
        sz = 128 * 256; transpose_cast_kernel<<<(sz + 255) / 256, 256, 0, stream>>>(Ws[0], Wst[0], 128, 256);
        sz = 256 * 256; transpose_cast_kernel<<<(sz + 255) / 256, 256, 0, stream>>>(Ws[1], Wst[1], 256, 256);
    }

    const bf16* hin_b = xb;
    float* hf[2] = {h1f, h2f};
    bf16*  hb[2] = {h1b, h2b};

    for (int l = 0; l < 3; l++) {
        int ns = NS[l], nd = ND[l], ne = NEg[l], cin = CIN[l], d = DPH[l];
        int hd = HEADS * d;

        dim3 g1((hd + 127) / 128, (ns + 127) / 128);
        gemm_mfma<0><<<g1, 256, 0, stream>>>(hin_b, Wt[l], nullptr, nullptr, fsb, nullptr, ns, hd, cin);

        el_er_kernel<<<ns, 256, 0, stream>>>(fsb, al[l], ar[l], elb, erb, nd, d);

        zero_int_kernel<<<256, 256, 0, stream>>>(counts, nd);
        hist_kernel<<<512, 256, 0, stream>>>(dstp[l], ne, counts);
        scan_kernel<<<1, 1024, 0, stream>>>(counts, offs, cursor, nd);
        scatter_kernel<<<512, 256, 0, stream>>>(srcp[l], dstp[l], ne, cursor, ssrc);

        attn_kernel<<<(nd + 3) / 4, 256, 0, stream>>>(elb, erb, offs, ssrc, alpha, nd);

        agg_kernel<<<(nd + 3) / 4, 256, 0, stream>>>(fsb, alpha, bb[l], offs, ssrc, rst, d, nd);

        if (l < 2) {
            dim3 g2((256 + 127) / 128, (nd + 127) / 128);
            gemm_mfma<1><<<g2, 256, 0, stream>>>(hin_b, Wst[l], rst, bs[l], hb[l], hf[l], nd, 256, cin);
            hin_b = hb[l];
        } else {
            final_kernel<<<nd, 64, 0, stream>>>(rst, h2f, Ws[l], bs[l], (float*)d_out);
        }
    }
}

// Round 4
// 955.937 us; speedup vs baseline: 1.7989x; 1.1830x over previous
//
#include <hip/hip_runtime.h>
#include <hip/hip_bf16.h>
#include <cmath>

#define HEADS 4
typedef __hip_bfloat16 bf16;
typedef short short8 __attribute__((ext_vector_type(8)));
typedef unsigned short us8 __attribute__((ext_vector_type(8)));
typedef float floatx4 __attribute__((ext_vector_type(4)));

__device__ inline float bf2f(unsigned short u) {
    union { unsigned u; float f; } c; c.u = ((unsigned)u) << 16; return c.f;
}
__device__ inline short f2bs(float f) {
    bf16 h = __float2bfloat16(f);
    return *reinterpret_cast<short*>(&h);
}

// Bt[n*K+k] = W[k*N+n], cast to bf16
__global__ void transpose_cast_kernel(const float* __restrict__ W, bf16* __restrict__ Bt, int K, int N)
{
    int i = blockIdx.x * blockDim.x + threadIdx.x;
    if (i >= K * N) return;
    int n = i / K, k = i % K;
    Bt[i] = __float2bfloat16(W[(size_t)k * N + n]);
}

// ---------------- MFMA GEMM: C[M,N] = A[M,K] @ Bt[N,K]^T ----------------
// AF32: A is float32 (converted during LDS staging). FUSE 1: elu(acc+add+bias) -> Cf,Cb.
template<int FUSE, int AF32>
__global__ __launch_bounds__(256)
void gemm_mfma(const void* __restrict__ Av, const bf16* __restrict__ Bt,
               const float* __restrict__ add, const float* __restrict__ bias,
               bf16* __restrict__ Cb, float* __restrict__ Cf,
               int M, int N, int K)
{
    const int BM = 128, BN = 128, BK = 32;
    __shared__ short As[BM * BK];
    __shared__ short Bs[BN * BK];
    int tid = threadIdx.x;
    int wave = tid >> 6, lane = tid & 63;
    int q = lane >> 4, r = lane & 15;
    int row0 = blockIdx.y * BM, col0 = blockIdx.x * BN;
    int wm = (wave >> 1) * 64, wn = (wave & 1) * 64;

    const short* As16 = (const short*)Av;
    const float* Af   = (const float*)Av;
    const short* Bs16 = (const short*)Bt;

    floatx4 zero = {0.f, 0.f, 0.f, 0.f};
    floatx4 acc[4][4];
#pragma unroll
    for (int i = 0; i < 4; i++)
#pragma unroll
        for (int j = 0; j < 4; j++) acc[i][j] = zero;

    for (int k0 = 0; k0 < K; k0 += BK) {
#pragma unroll
        for (int rep = 0; rep < 2; rep++) {
            int i = tid + 256 * rep;
            int rrow = i >> 2, chunk = i & 3;
            int grow = row0 + rrow;
            short8 v = {0, 0, 0, 0, 0, 0, 0, 0};
            if (AF32) {
                float4 v0 = {0, 0, 0, 0}, v1 = {0, 0, 0, 0};
                if (grow < M) {
                    v0 = *(const float4*)&Af[(size_t)grow * K + k0 + chunk * 8];
                    v1 = *(const float4*)&Af[(size_t)grow * K + k0 + chunk * 8 + 4];
                }
                v[0] = f2bs(v0.x); v[1] = f2bs(v0.y); v[2] = f2bs(v0.z); v[3] = f2bs(v0.w);
                v[4] = f2bs(v1.x); v[5] = f2bs(v1.y); v[6] = f2bs(v1.z); v[7] = f2bs(v1.w);
            } else {
                if (grow < M) v = *(const short8*)&As16[(size_t)grow * K + k0 + chunk * 8];
            }
            *(short8*)&As[rrow * BK + chunk * 8] = v;
        }
#pragma unroll
        for (int rep = 0; rep < 2; rep++) {
            int i = tid + 256 * rep;
            int rrow = i >> 2, chunk = i & 3;
            int gcol = col0 + rrow;
            short8 v = {0, 0, 0, 0, 0, 0, 0, 0};
            if (gcol < N) v = *(const short8*)&Bs16[(size_t)gcol * K + k0 + chunk * 8];
            *(short8*)&Bs[rrow * BK + chunk * 8] = v;
        }
        __syncthreads();
        short8 af[4], bfr[4];
#pragma unroll
        for (int mt = 0; mt < 4; mt++) af[mt] = *(short8*)&As[(wm + mt * 16 + r) * BK + q * 8];
#pragma unroll
        for (int nt = 0; nt < 4; nt++) bfr[nt] = *(short8*)&Bs[(wn + nt * 16 + r) * BK + q * 8];
#pragma unroll
        for (int mt = 0; mt < 4; mt++)
#pragma unroll
            for (int nt = 0; nt < 4; nt++)
                acc[mt][nt] = __builtin_amdgcn_mfma_f32_16x16x32_bf16(af[mt], bfr[nt], acc[mt][nt], 0, 0, 0);
        __syncthreads();
    }

#pragma unroll
    for (int mt = 0; mt < 4; mt++) {
#pragma unroll
        for (int nt = 0; nt < 4; nt++) {
            int gcol = col0 + wn + nt * 16 + r;
            if (gcol >= N) continue;
#pragma unroll
            for (int e = 0; e < 4; e++) {
                int grow = row0 + wm + mt * 16 + q * 4 + e;
                if (grow >= M) continue;
                float v = acc[mt][nt][e];
                size_t idx = (size_t)grow * N + gcol;
                if (FUSE == 1) {
                    v += add[idx] + bias[gcol];
                    v = (v > 0.f) ? v : (__expf(v) - 1.f);
                    Cf[idx] = v;
                    Cb[idx] = __float2bfloat16(v);
                } else {
                    Cb[idx] = __float2bfloat16(v);
                }
            }
        }
    }
}

// ---------------- el/er, D=64 specialization: grid-stride, one wave per node ----------------
__global__ void el_er64_kernel(const bf16* __restrict__ fs, const float* __restrict__ al,
                               const float* __restrict__ ar, float* __restrict__ el,
                               float* __restrict__ er, int ns, int nd)
{
    int lane = threadIdx.x & 63;
    int gw = (blockIdx.x * blockDim.x + threadIdx.x) >> 6;
    int nw = (gridDim.x * blockDim.x) >> 6;
    int h = lane >> 4, sub = lane & 15;
    float4 alv = *(const float4*)&al[h * 64 + sub * 4];
    float4 arv = *(const float4*)&ar[h * 64 + sub * 4];
    const unsigned short* fsu = (const unsigned short*)fs;
    for (int n = gw; n < ns; n += nw) {
        ushort4 f = *(const ushort4*)&fsu[(size_t)n * 256 + lane * 4];
        float x0 = bf2f(f.x), x1 = bf2f(f.y), x2 = bf2f(f.z), x3 = bf2f(f.w);
        float pl = x0 * alv.x + x1 * alv.y + x2 * alv.z + x3 * alv.w;
        float pr = x0 * arv.x + x1 * arv.y + x2 * arv.z + x3 * arv.w;
#pragma unroll
        for (int off = 1; off < 16; off <<= 1) {
            pl += __shfl_xor(pl, off);
            pr += __shfl_xor(pr, off);
        }
        if (sub == 0) {
            el[n * 4 + h] = pl;
            if (n < nd) er[n * 4 + h] = pr;
        }
    }
}

// generic (layer 2, D=47)
__global__ void el_er_kernel(const bf16* __restrict__ fs, const float* __restrict__ al,
                             const float* __restrict__ ar, float* __restrict__ el,
                             float* __restrict__ er, int nd, int D)
{
    int n = blockIdx.x;
    int h = threadIdx.x >> 6;
    int d = threadIdx.x & 63;
    int HD = HEADS * D;
    float v = 0.f, a = 0.f, rr = 0.f;
    if (d < D) {
        v = __bfloat162float(fs[(size_t)n * HD + h * D + d]);
        a = al[h * D + d];
        rr = ar[h * D + d];
    }
    float pl = v * a, pr = v * rr;
    for (int off = 32; off; off >>= 1) {
        pl += __shfl_down(pl, off);
        pr += __shfl_down(pr, off);
    }
    if (d == 0) {
        el[n * HEADS + h] = pl;
        if (n < nd) er[n * HEADS + h] = pr;
    }
}

// ---------------- CSR build ----------------
__global__ void zero_int_kernel(int* p, int n)
{
    for (int i = blockIdx.x * blockDim.x + threadIdx.x; i < n; i += gridDim.x * blockDim.x)
        p[i] = 0;
}

__global__ void hist_kernel(const int* __restrict__ dst, int ne, int* __restrict__ cnt)
{
    for (int i = blockIdx.x * blockDim.x + threadIdx.x; i < ne; i += gridDim.x * blockDim.x)
        atomicAdd(&cnt[dst[i]], 1);
}

__global__ void scan_kernel(const int* __restrict__ cnt, int* __restrict__ offs,
                            int* __restrict__ cursor, int nd)
{
    __shared__ int sums[1024];
    int tid = threadIdx.x;
    int chunk = (nd + 1023) >> 10;
    int b0 = min(tid * chunk, nd), b1 = min(b0 + chunk, nd);
    int s = 0;
    for (int i = b0; i < b1; i++) s += cnt[i];
    sums[tid] = s;
    __syncthreads();
    for (int off = 1; off < 1024; off <<= 1) {
        int t = (tid >= off) ? sums[tid - off] : 0;
        __syncthreads();
        sums[tid] += t;
        __syncthreads();
    }
    int run = (tid == 0) ? 0 : sums[tid - 1];
    for (int i = b0; i < b1; i++) {
        offs[i] = run; cursor[i] = run;
        run += cnt[i];
    }
    if (tid == 0) offs[nd] = sums[1023];
}

__global__ void scatter_kernel(const int* __restrict__ src, const int* __restrict__ dst,
                               int ne, int* __restrict__ cursor, int* __restrict__ ssrc)
{
    for (int i = blockIdx.x * blockDim.x + threadIdx.x; i < ne; i += gridDim.x * blockDim.x) {
        int d = dst[i];
        int p = atomicAdd(&cursor[d], 1);
        ssrc[p] = src[i];
    }
}

// ---------------- attention: per-dst softmax over edges, writes normalized alpha ----------------
__global__ void attn_kernel(const float* __restrict__ el, const float* __restrict__ er,
                            const int* __restrict__ offs, const int* __restrict__ ssrc,
                            float4* __restrict__ alpha, int nd)
{
    int wave = threadIdx.x >> 6, lane = threadIdx.x & 63;
    int n = blockIdx.x * 4 + wave;
    if (n >= nd) return;
    int s0 = offs[n], s1 = offs[n + 1];
    float4 erv = *(const float4*)&er[(size_t)n * 4];

    float m0 = -INFINITY, m1 = -INFINITY, m2 = -INFINITY, m3 = -INFINITY;
    for (int i = s0 + lane; i < s1; i += 64) {
        int sid = ssrc[i];
        float4 ev = *(const float4*)&el[(size_t)sid * 4];
        float e0 = ev.x + erv.x; e0 = (e0 > 0.f) ? e0 : 0.2f * e0;
        float e1 = ev.y + erv.y; e1 = (e1 > 0.f) ? e1 : 0.2f * e1;
        float e2 = ev.z + erv.z; e2 = (e2 > 0.f) ? e2 : 0.2f * e2;
        float e3 = ev.w + erv.w; e3 = (e3 > 0.f) ? e3 : 0.2f * e3;
        alpha[i] = make_float4(e0, e1, e2, e3);
        m0 = fmaxf(m0, e0); m1 = fmaxf(m1, e1); m2 = fmaxf(m2, e2); m3 = fmaxf(m3, e3);
    }
#pragma unroll
    for (int off = 32; off; off >>= 1) {
        m0 = fmaxf(m0, __shfl_xor(m0, off));
        m1 = fmaxf(m1, __shfl_xor(m1, off));
        m2 = fmaxf(m2, __shfl_xor(m2, off));
        m3 = fmaxf(m3, __shfl_xor(m3, off));
    }
    float t0 = 0.f, t1 = 0.f, t2 = 0.f, t3 = 0.f;
    for (int i = s0 + lane; i < s1; i += 64) {
        float4 e = alpha[i];
        float p0 = __expf(e.x - m0), p1 = __expf(e.y - m1);
        float p2 = __expf(e.z - m2), p3 = __expf(e.w - m3);
        alpha[i] = make_float4(p0, p1, p2, p3);
        t0 += p0; t1 += p1; t2 += p2; t3 += p3;
    }
#pragma unroll
    for (int off = 32; off; off >>= 1) {
        t0 += __shfl_xor(t0, off);
        t1 += __shfl_xor(t1, off);
        t2 += __shfl_xor(t2, off);
        t3 += __shfl_xor(t3, off);
    }
    float r0 = (t0 > 0.f) ? 1.f / t0 : 0.f;
    float r1 = (t1 > 0.f) ? 1.f / t1 : 0.f;
    float r2 = (t2 > 0.f) ? 1.f / t2 : 0.f;
    float r3 = (t3 > 0.f) ? 1.f / t3 : 0.f;
    for (int i = s0 + lane; i < s1; i += 64) {
        float4 pv = alpha[i];
        alpha[i] = make_float4(pv.x * r0, pv.y * r1, pv.z * r2, pv.w * r3);
    }
}

// ---------------- aggregation D=64 (HD=256): half-wave per edge, 2 edges/iter, pipelined ----------------
__global__ __launch_bounds__(256)
void agg64_kernel(const bf16* __restrict__ fs, const float4* __restrict__ alpha,
                  const float* __restrict__ b,
                  const int* __restrict__ offs, const int* __restrict__ ssrc,
                  float* __restrict__ rst, int nd)
{
    int wave = threadIdx.x >> 6, lane = threadIdx.x & 63;
    int n = blockIdx.x * 4 + wave;
    if (n >= nd) return;
    int half = lane >> 5, sub = lane & 31;
    int head = sub >> 3;                       // 8 lanes per head (8 elems/lane, D=64)
    int s0 = offs[n], s1 = offs[n + 1];
    int cnt = s1 - s0;
    const unsigned short* fsu = (const unsigned short*)fs;

    float acc[8];
#pragma unroll
    for (int j = 0; j < 8; j++) acc[j] = 0.f;

    int npairs = cnt >> 1;
    int i = s0 + half;
    if (npairs > 0) {
        // prologue
        int sid = ssrc[i];
        float4 av = alpha[i];
        us8 f = *(const us8*)&fsu[(size_t)sid * 256 + sub * 8];
        for (int p = 1; p < npairs; p++) {
            i += 2;
            int sid2 = ssrc[i];
            float4 av2 = alpha[i];
            us8 f2 = *(const us8*)&fsu[(size_t)sid2 * 256 + sub * 8];
            float a = (head == 0) ? av.x : (head == 1) ? av.y : (head == 2) ? av.z : av.w;
#pragma unroll
            for (int j = 0; j < 8; j++) acc[j] += a * bf2f(f[j]);
            av = av2; f = f2;
        }
        float a = (head == 0) ? av.x : (head == 1) ? av.y : (head == 2) ? av.z : av.w;
#pragma unroll
        for (int j = 0; j < 8; j++) acc[j] += a * bf2f(f[j]);
    }
    if (cnt & 1) {
        int e = s1 - 1;
        int sid = ssrc[e];
        float4 av = alpha[e];
        us8 f = *(const us8*)&fsu[(size_t)sid * 256 + sub * 8];
        float a = (head == 0) ? av.x : (head == 1) ? av.y : (head == 2) ? av.z : av.w;
        if (half) a = 0.f;
#pragma unroll
        for (int j = 0; j < 8; j++) acc[j] += a * bf2f(f[j]);
    }
    // combine halves
#pragma unroll
    for (int j = 0; j < 8; j++) acc[j] += __shfl_xor(acc[j], 32);
    if (half == 0) {
        float4 b0 = *(const float4*)&b[sub * 8];
        float4 b1 = *(const float4*)&b[sub * 8 + 4];
        float4 o0 = make_float4(acc[0] + b0.x, acc[1] + b0.y, acc[2] + b0.z, acc[3] + b0.w);
        float4 o1 = make_float4(acc[4] + b1.x, acc[5] + b1.y, acc[6] + b1.z, acc[7] + b1.w);
        *(float4*)&rst[(size_t)n * 256 + sub * 8] = o0;
        *(float4*)&rst[(size_t)n * 256 + sub * 8 + 4] = o1;
    }
}

// generic aggregation (layer 2, D=47)
__global__ void agg_kernel(const bf16* __restrict__ fs, const float4* __restrict__ alpha,
                           const float* __restrict__ b,
                           const int* __restrict__ offs, const int* __restrict__ ssrc,
                           float* __restrict__ rst, int D, int nd)
{
    int wave = threadIdx.x >> 6, lane = threadIdx.x & 63;
    int n = blockIdx.x * 4 + wave;
    if (n >= nd) return;
    int HD = HEADS * D;
    bool act = (4 * lane) < HD;
    int h_[4];
#pragma unroll
    for (int j = 0; j < 4; j++) {
        int e = 4 * lane + j;
        h_[j] = (e < HD) ? (e / D) : 0;
    }
    float acc[4] = {0.f, 0.f, 0.f, 0.f};
    int s0 = offs[n], s1 = offs[n + 1];
    const unsigned short* fsu = (const unsigned short*)fs;
    for (int i = s0; i < s1; i++) {
        int sid = ssrc[i];
        float4 av = alpha[i];
        float a_[4] = {av.x, av.y, av.z, av.w};
        ushort4 f = {0, 0, 0, 0};
        if (act) f = *(const ushort4*)&fsu[(size_t)sid * HD + 4 * lane];
        unsigned short fa[4] = {f.x, f.y, f.z, f.w};
#pragma unroll
        for (int j = 0; j < 4; j++)
            acc[j] += a_[h_[j]] * bf2f(fa[j]);
    }
    if (act) {
#pragma unroll
        for (int j = 0; j < 4; j++) {
            int e4 = 4 * lane + j;
            rst[(size_t)n * HD + e4] = acc[j] + b[e4];
        }
    }
}

// ---------------- final layer ----------------
__global__ void final_kernel(const float* __restrict__ rst2, const float* __restrict__ h2,
                             const float* __restrict__ Ws, const float* __restrict__ bs,
                             float* __restrict__ out)
{
    const int K = 256, C = 47;
    int n = blockIdx.x;
    int c = threadIdx.x;
    float v = -INFINITY;
    if (c < C) {
        float dot = 0.f;
        for (int k = 0; k < K; k++) dot += h2[(size_t)n * K + k] * Ws[k * C + c];
        float mean = 0.f;
#pragma unroll
        for (int hh = 0; hh < HEADS; hh++) mean += rst2[(size_t)n * HEADS * C + hh * C + c];
        mean *= 0.25f;
        v = mean + dot + bs[c];
    }
    float mx = v;
    for (int off = 32; off; off >>= 1) mx = fmaxf(mx, __shfl_xor(mx, off));
    float ex = (c < C) ? __expf(v - mx) : 0.f;
    float sum = ex;
    for (int off = 32; off; off >>= 1) sum += __shfl_xor(sum, off);
    if (c < C) out[n * C + c] = v - mx - logf(sum);
}

extern "C" void kernel_launch(void* const* d_in, const int* in_sizes, int n_in,
                              void* d_out, int out_size, void* d_ws, size_t ws_size,
                              hipStream_t stream)
{
    const float* x = (const float*)d_in[0];
    const float* W[3]  = {(const float*)d_in[1],  (const float*)d_in[7],  (const float*)d_in[13]};
    const float* al[3] = {(const float*)d_in[2],  (const float*)d_in[8],  (const float*)d_in[14]};
    const float* ar[3] = {(const float*)d_in[3],  (const float*)d_in[9],  (const float*)d_in[15]};
    const float* bb[3] = {(const float*)d_in[4],  (const float*)d_in[10], (const float*)d_in[16]};
    const float* Ws[3] = {(const float*)d_in[5],  (const float*)d_in[11], (const float*)d_in[17]};
    const float* bs[3] = {(const float*)d_in[6],  (const float*)d_in[12], (const float*)d_in[18]};
    const int* srcp[3] = {(const int*)d_in[19], (const int*)d_in[21], (const int*)d_in[23]};
    const int* dstp[3] = {(const int*)d_in[20], (const int*)d_in[22], (const int*)d_in[24]};

    const int NS[3]  = {200000, 50000, 10000};
    const int ND[3]  = {50000, 10000, 2048};
    const int NEg[3] = {800000, 400000, 100000};
    const int CIN[3] = {128, 256, 256};
    const int DPH[3] = {64, 64, 47};

    char* p = (char*)d_ws;
    auto alloc = [&](size_t bytes) -> void* {
        void* r = (void*)p;
        p += (bytes + 255) & ~(size_t)255;
        return r;
    };
    bf16*  fsb  = (bf16*)alloc((size_t)200000 * 256 * 2);
    float* h1f  = (float*)alloc((size_t)50000 * 256 * 4);
    bf16*  h1b  = (bf16*)alloc((size_t)50000 * 256 * 2);
    float* h2f  = (float*)alloc((size_t)10000 * 256 * 4);
    bf16*  h2b  = (bf16*)alloc((size_t)10000 * 256 * 2);
    float* rst  = (float*)alloc((size_t)50000 * 256 * 4);
    float* elb  = (float*)alloc((size_t)200000 * 4 * 4);
    float* erb  = (float*)alloc((size_t)50000 * 4 * 4);
    float4* alpha = (float4*)alloc((size_t)800000 * 16);
    bf16*  Wt[3];  bf16* Wst[2];
    Wt[0]  = (bf16*)alloc(128 * 256 * 2);
    Wt[1]  = (bf16*)alloc(256 * 256 * 2);
    Wt[2]  = (bf16*)alloc(256 * 188 * 2);
    Wst[0] = (bf16*)alloc(128 * 256 * 2);
    Wst[1] = (bf16*)alloc(256 * 256 * 2);
    int* counts = (int*)alloc(50000 * 4);
    int* offs   = (int*)alloc(50001 * 4);
    int* cursor = (int*)alloc(50000 * 4);
    int* ssrc   = (int*)alloc(800000 * 4);

    {
        int sz;
        sz = 128 * 256; transpose_cast_kernel<<<(sz + 255) / 256, 256, 0, stream>>>(W[0],  Wt[0],  128, 256);
        sz = 256 * 256; transpose_cast_kernel<<<(sz + 255) / 256, 256, 0, stream>>>(W[1],  Wt[1],  256, 256);
        sz = 256 * 188; transpose_cast_kernel<<<(sz + 255) / 256, 256, 0, stream>>>(W[2],  Wt[2],  256, 188);
        sz = 128 * 256; transpose_cast_kernel<<<(sz + 255) / 256, 256, 0, stream>>>(Ws[0], Wst[0], 128, 256);
        sz = 256 * 256; transpose_cast_kernel<<<(sz + 255) / 256, 256, 0, stream>>>(Ws[1], Wst[1], 256, 256);
    }

    const void* hin = (const void*)x;   // layer 0: f32; layers 1,2: bf16
    float* hf[2] = {h1f, h2f};
    bf16*  hb[2] = {h1b, h2b};

    for (int l = 0; l < 3; l++) {
        int ns = NS[l], nd = ND[l], ne = NEg[l], cin = CIN[l], d = DPH[l];
        int hd = HEADS * d;

        // 1. fs = hin @ W
        dim3 g1((hd + 127) / 128, (ns + 127) / 128);
        if (l == 0)
            gemm_mfma<0, 1><<<g1, 256, 0, stream>>>(hin, Wt[l], nullptr, nullptr, fsb, nullptr, ns, hd, cin);
        else
            gemm_mfma<0, 0><<<g1, 256, 0, stream>>>(hin, Wt[l], nullptr, nullptr, fsb, nullptr, ns, hd, cin);

        // 2. attention logit halves
        if (d == 64)
            el_er64_kernel<<<1024, 256, 0, stream>>>(fsb, al[l], ar[l], elb, erb, ns, nd);
        else
            el_er_kernel<<<ns, 256, 0, stream>>>(fsb, al[l], ar[l], elb, erb, nd, d);

        // 3. CSR build
        zero_int_kernel<<<256, 256, 0, stream>>>(counts, nd);
        hist_kernel<<<512, 256, 0, stream>>>(dstp[l], ne, counts);
        scan_kernel<<<1, 1024, 0, stream>>>(counts, offs, cursor, nd);
        scatter_kernel<<<512, 256, 0, stream>>>(srcp[l], dstp[l], ne, cursor, ssrc);

        // 4. normalized attention weights
        attn_kernel<<<(nd + 3) / 4, 256, 0, stream>>>(elb, erb, offs, ssrc, alpha, nd);

        // 5. aggregation
        if (d == 64)
            agg64_kernel<<<(nd + 3) / 4, 256, 0, stream>>>(fsb, alpha, bb[l], offs, ssrc, rst, nd);
        else
            agg_kernel<<<(nd + 3) / 4, 256, 0, stream>>>(fsb, alpha, bb[l], offs, ssrc, rst, d, nd);

        // 6. skip connection
        if (l < 2) {
            dim3 g2((256 + 127) / 128, (nd + 127) / 128);
            if (l == 0)
                gemm_mfma<1, 1><<<g2, 256, 0, stream>>>(hin, Wst[l], rst, bs[l], hb[l], hf[l], nd, 256, cin);
            else
                gemm_mfma<1, 0><<<g2, 256, 0, stream>>>(hin, Wst[l], rst, bs[l], hb[l], hf[l], nd, 256, cin);
            hin = (const void*)hb[l];
        } else {
            final_kernel<<<nd, 64, 0, stream>>>(rst, h2f, Ws[l], bs[l], (float*)d_out);
        }
    }
}

// Round 5
// 847.401 us; speedup vs baseline: 2.0293x; 1.1281x over previous
//
#include <hip/hip_runtime.h>
#include <hip/hip_bf16.h>
#include <cmath>

#define HEADS 4
typedef __hip_bfloat16 bf16;
typedef short short8 __attribute__((ext_vector_type(8)));
typedef unsigned short us8 __attribute__((ext_vector_type(8)));
typedef float floatx4 __attribute__((ext_vector_type(4)));

__device__ inline float bf2f(unsigned short u) {
    union { unsigned u; float f; } c; c.u = ((unsigned)u) << 16; return c.f;
}
__device__ inline short f2bs(float f) {
    bf16 h = __float2bfloat16(f);
    return *reinterpret_cast<short*>(&h);
}

// Bt[n*K+k] = W[k*N+n], cast to bf16
__global__ void transpose_cast_kernel(const float* __restrict__ W, bf16* __restrict__ Bt, int K, int N)
{
    int i = blockIdx.x * blockDim.x + threadIdx.x;
    if (i >= K * N) return;
    int n = i / K, k = i % K;
    Bt[i] = __float2bfloat16(W[(size_t)k * N + n]);
}

// ---------------- MFMA GEMM: C[M,N] = A[M,K] @ Bt[N,K]^T ----------------
template<int FUSE, int AF32>
__global__ __launch_bounds__(256)
void gemm_mfma(const void* __restrict__ Av, const bf16* __restrict__ Bt,
               const float* __restrict__ add, const float* __restrict__ bias,
               bf16* __restrict__ Cb, float* __restrict__ Cf,
               int M, int N, int K)
{
    const int BM = 128, BN = 128, BK = 32;
    __shared__ short As[BM * BK];
    __shared__ short Bs[BN * BK];
    int tid = threadIdx.x;
    int wave = tid >> 6, lane = tid & 63;
    int q = lane >> 4, r = lane & 15;
    int row0 = blockIdx.y * BM, col0 = blockIdx.x * BN;
    int wm = (wave >> 1) * 64, wn = (wave & 1) * 64;

    const short* As16 = (const short*)Av;
    const float* Af   = (const float*)Av;
    const short* Bs16 = (const short*)Bt;

    floatx4 zero = {0.f, 0.f, 0.f, 0.f};
    floatx4 acc[4][4];
#pragma unroll
    for (int i = 0; i < 4; i++)
#pragma unroll
        for (int j = 0; j < 4; j++) acc[i][j] = zero;

    for (int k0 = 0; k0 < K; k0 += BK) {
#pragma unroll
        for (int rep = 0; rep < 2; rep++) {
            int i = tid + 256 * rep;
            int rrow = i >> 2, chunk = i & 3;
            int grow = row0 + rrow;
            short8 v = {0, 0, 0, 0, 0, 0, 0, 0};
            if (AF32) {
                float4 v0 = {0, 0, 0, 0}, v1 = {0, 0, 0, 0};
                if (grow < M) {
                    v0 = *(const float4*)&Af[(size_t)grow * K + k0 + chunk * 8];
                    v1 = *(const float4*)&Af[(size_t)grow * K + k0 + chunk * 8 + 4];
                }
                v[0] = f2bs(v0.x); v[1] = f2bs(v0.y); v[2] = f2bs(v0.z); v[3] = f2bs(v0.w);
                v[4] = f2bs(v1.x); v[5] = f2bs(v1.y); v[6] = f2bs(v1.z); v[7] = f2bs(v1.w);
            } else {
                if (grow < M) v = *(const short8*)&As16[(size_t)grow * K + k0 + chunk * 8];
            }
            *(short8*)&As[rrow * BK + chunk * 8] = v;
        }
#pragma unroll
        for (int rep = 0; rep < 2; rep++) {
            int i = tid + 256 * rep;
            int rrow = i >> 2, chunk = i & 3;
            int gcol = col0 + rrow;
            short8 v = {0, 0, 0, 0, 0, 0, 0, 0};
            if (gcol < N) v = *(const short8*)&Bs16[(size_t)gcol * K + k0 + chunk * 8];
            *(short8*)&Bs[rrow * BK + chunk * 8] = v;
        }
        __syncthreads();
        short8 af[4], bfr[4];
#pragma unroll
        for (int mt = 0; mt < 4; mt++) af[mt] = *(short8*)&As[(wm + mt * 16 + r) * BK + q * 8];
#pragma unroll
        for (int nt = 0; nt < 4; nt++) bfr[nt] = *(short8*)&Bs[(wn + nt * 16 + r) * BK + q * 8];
#pragma unroll
        for (int mt = 0; mt < 4; mt++)
#pragma unroll
            for (int nt = 0; nt < 4; nt++)
                acc[mt][nt] = __builtin_amdgcn_mfma_f32_16x16x32_bf16(af[mt], bfr[nt], acc[mt][nt], 0, 0, 0);
        __syncthreads();
    }

#pragma unroll
    for (int mt = 0; mt < 4; mt++) {
#pragma unroll
        for (int nt = 0; nt < 4; nt++) {
            int gcol = col0 + wn + nt * 16 + r;
            if (gcol >= N) continue;
#pragma unroll
            for (int e = 0; e < 4; e++) {
                int grow = row0 + wm + mt * 16 + q * 4 + e;
                if (grow >= M) continue;
                float v = acc[mt][nt][e];
                size_t idx = (size_t)grow * N + gcol;
                if (FUSE == 1) {
                    v += add[idx] + bias[gcol];
                    v = (v > 0.f) ? v : (__expf(v) - 1.f);
                    Cf[idx] = v;
                    Cb[idx] = __float2bfloat16(v);
                } else {
                    Cb[idx] = __float2bfloat16(v);
                }
            }
        }
    }
}

// ---------------- el/er, D=64 specialization ----------------
__global__ void el_er64_kernel(const bf16* __restrict__ fs, const float* __restrict__ al,
                               const float* __restrict__ ar, float* __restrict__ el,
                               float* __restrict__ er, int ns, int nd)
{
    int lane = threadIdx.x & 63;
    int gw = (blockIdx.x * blockDim.x + threadIdx.x) >> 6;
    int nw = (gridDim.x * blockDim.x) >> 6;
    int h = lane >> 4, sub = lane & 15;
    float4 alv = *(const float4*)&al[h * 64 + sub * 4];
    float4 arv = *(const float4*)&ar[h * 64 + sub * 4];
    const unsigned short* fsu = (const unsigned short*)fs;
    for (int n = gw; n < ns; n += nw) {
        ushort4 f = *(const ushort4*)&fsu[(size_t)n * 256 + lane * 4];
        float x0 = bf2f(f.x), x1 = bf2f(f.y), x2 = bf2f(f.z), x3 = bf2f(f.w);
        float pl = x0 * alv.x + x1 * alv.y + x2 * alv.z + x3 * alv.w;
        float pr = x0 * arv.x + x1 * arv.y + x2 * arv.z + x3 * arv.w;
#pragma unroll
        for (int off = 1; off < 16; off <<= 1) {
            pl += __shfl_xor(pl, off);
            pr += __shfl_xor(pr, off);
        }
        if (sub == 0) {
            el[n * 4 + h] = pl;
            if (n < nd) er[n * 4 + h] = pr;
        }
    }
}

// generic (layer 2, D=47)
__global__ void el_er_kernel(const bf16* __restrict__ fs, const float* __restrict__ al,
                             const float* __restrict__ ar, float* __restrict__ el,
                             float* __restrict__ er, int nd, int D)
{
    int n = blockIdx.x;
    int h = threadIdx.x >> 6;
    int d = threadIdx.x & 63;
    int HD = HEADS * D;
    float v = 0.f, a = 0.f, rr = 0.f;
    if (d < D) {
        v = __bfloat162float(fs[(size_t)n * HD + h * D + d]);
        a = al[h * D + d];
        rr = ar[h * D + d];
    }
    float pl = v * a, pr = v * rr;
    for (int off = 32; off; off >>= 1) {
        pl += __shfl_down(pl, off);
        pr += __shfl_down(pr, off);
    }
    if (d == 0) {
        el[n * HEADS + h] = pl;
        if (n < nd) er[n * HEADS + h] = pr;
    }
}

// ---------------- CSR build ----------------
__global__ void zero_int_kernel(int* p, int n)
{
    for (int i = blockIdx.x * blockDim.x + threadIdx.x; i < n; i += gridDim.x * blockDim.x)
        p[i] = 0;
}

__global__ void hist_kernel(const int* __restrict__ dst, int ne, int* __restrict__ cnt)
{
    for (int i = blockIdx.x * blockDim.x + threadIdx.x; i < ne; i += gridDim.x * blockDim.x)
        atomicAdd(&cnt[dst[i]], 1);
}

// 3-phase device-wide exclusive scan (replaces 110us single-block scan)
__global__ void scan_a_kernel(const int* __restrict__ cnt, int* __restrict__ bsum, int nd)
{
    __shared__ int sdata[256];
    int i = blockIdx.x * 256 + threadIdx.x;
    sdata[threadIdx.x] = (i < nd) ? cnt[i] : 0;
    __syncthreads();
    for (int off = 128; off; off >>= 1) {
        if (threadIdx.x < off) sdata[threadIdx.x] += sdata[threadIdx.x + off];
        __syncthreads();
    }
    if (threadIdx.x == 0) bsum[blockIdx.x] = sdata[0];
}

__global__ void scan_b_kernel(const int* __restrict__ bsum, int* __restrict__ bpre,
                              int* __restrict__ offs, int nb, int nd)
{
    __shared__ int sdata[256];
    int tid = threadIdx.x;
    int v = (tid < nb) ? bsum[tid] : 0;
    sdata[tid] = v;
    __syncthreads();
    for (int off = 1; off < 256; off <<= 1) {
        int t = (tid >= off) ? sdata[tid - off] : 0;
        __syncthreads();
        sdata[tid] += t;
        __syncthreads();
    }
    if (tid < nb) bpre[tid] = sdata[tid] - v;  // exclusive
    if (tid == 255) offs[nd] = sdata[255];     // total
}

__global__ void scan_c_kernel(const int* __restrict__ cnt, const int* __restrict__ bpre,
                              int* __restrict__ offs, int* __restrict__ cursor, int nd)
{
    __shared__ int sdata[256];
    int tid = threadIdx.x;
    int i = blockIdx.x * 256 + tid;
    int v = (i < nd) ? cnt[i] : 0;
    sdata[tid] = v;
    __syncthreads();
    for (int off = 1; off < 256; off <<= 1) {
        int t = (tid >= off) ? sdata[tid - off] : 0;
        __syncthreads();
        sdata[tid] += t;
        __syncthreads();
    }
    if (i < nd) {
        int e = bpre[blockIdx.x] + sdata[tid] - v;
        offs[i] = e; cursor[i] = e;
    }
}

__global__ void scatter_kernel(const int* __restrict__ src, const int* __restrict__ dst,
                               int ne, int* __restrict__ cursor, int* __restrict__ ssrc)
{
    for (int i = blockIdx.x * blockDim.x + threadIdx.x; i < ne; i += gridDim.x * blockDim.x) {
        int d = dst[i];
        int p = atomicAdd(&cursor[d], 1);
        ssrc[p] = src[i];
    }
}

// ---------------- attention: per-dst softmax over edges, writes normalized alpha ----------------
__global__ void attn_kernel(const float* __restrict__ el, const float* __restrict__ er,
                            const int* __restrict__ offs, const int* __restrict__ ssrc,
                            float4* __restrict__ alpha, int nd)
{
    int wave = threadIdx.x >> 6, lane = threadIdx.x & 63;
    int n = blockIdx.x * 4 + wave;
    if (n >= nd) return;
    int s0 = offs[n], s1 = offs[n + 1];
    float4 erv = *(const float4*)&er[(size_t)n * 4];

    float m0 = -INFINITY, m1 = -INFINITY, m2 = -INFINITY, m3 = -INFINITY;
    for (int i = s0 + lane; i < s1; i += 64) {
        int sid = ssrc[i];
        float4 ev = *(const float4*)&el[(size_t)sid * 4];
        float e0 = ev.x + erv.x; e0 = (e0 > 0.f) ? e0 : 0.2f * e0;
        float e1 = ev.y + erv.y; e1 = (e1 > 0.f) ? e1 : 0.2f * e1;
        float e2 = ev.z + erv.z; e2 = (e2 > 0.f) ? e2 : 0.2f * e2;
        float e3 = ev.w + erv.w; e3 = (e3 > 0.f) ? e3 : 0.2f * e3;
        alpha[i] = make_float4(e0, e1, e2, e3);
        m0 = fmaxf(m0, e0); m1 = fmaxf(m1, e1); m2 = fmaxf(m2, e2); m3 = fmaxf(m3, e3);
    }
#pragma unroll
    for (int off = 32; off; off >>= 1) {
        m0 = fmaxf(m0, __shfl_xor(m0, off));
        m1 = fmaxf(m1, __shfl_xor(m1, off));
        m2 = fmaxf(m2, __shfl_xor(m2, off));
        m3 = fmaxf(m3, __shfl_xor(m3, off));
    }
    float t0 = 0.f, t1 = 0.f, t2 = 0.f, t3 = 0.f;
    for (int i = s0 + lane; i < s1; i += 64) {
        float4 e = alpha[i];
        float p0 = __expf(e.x - m0), p1 = __expf(e.y - m1);
        float p2 = __expf(e.z - m2), p3 = __expf(e.w - m3);
        alpha[i] = make_float4(p0, p1, p2, p3);
        t0 += p0; t1 += p1; t2 += p2; t3 += p3;
    }
#pragma unroll
    for (int off = 32; off; off >>= 1) {
        t0 += __shfl_xor(t0, off);
        t1 += __shfl_xor(t1, off);
        t2 += __shfl_xor(t2, off);
        t3 += __shfl_xor(t3, off);
    }
    float r0 = (t0 > 0.f) ? 1.f / t0 : 0.f;
    float r1 = (t1 > 0.f) ? 1.f / t1 : 0.f;
    float r2 = (t2 > 0.f) ? 1.f / t2 : 0.f;
    float r3 = (t3 > 0.f) ? 1.f / t3 : 0.f;
    for (int i = s0 + lane; i < s1; i += 64) {
        float4 pv = alpha[i];
        alpha[i] = make_float4(pv.x * r0, pv.y * r1, pv.z * r2, pv.w * r3);
    }
}

// ---------------- aggregation D=64 (HD=256): half-wave per edge ----------------
__global__ __launch_bounds__(256)
void agg64_kernel(const bf16* __restrict__ fs, const float4* __restrict__ alpha,
                  const float* __restrict__ b,
                  const int* __restrict__ offs, const int* __restrict__ ssrc,
                  float* __restrict__ rst, int nd)
{
    int wave = threadIdx.x >> 6, lane = threadIdx.x & 63;
    int n = blockIdx.x * 4 + wave;
    if (n >= nd) return;
    int half = lane >> 5, sub = lane & 31;
    int head = sub >> 3;
    int s0 = offs[n], s1 = offs[n + 1];
    int cnt = s1 - s0;
    const unsigned short* fsu = (const unsigned short*)fs;

    float acc[8];
#pragma unroll
    for (int j = 0; j < 8; j++) acc[j] = 0.f;

    int npairs = cnt >> 1;
    int i = s0 + half;
    if (npairs > 0) {
        int sid = ssrc[i];
        float4 av = alpha[i];
        us8 f = *(const us8*)&fsu[(size_t)sid * 256 + sub * 8];
        for (int p = 1; p < npairs; p++) {
            i += 2;
            int sid2 = ssrc[i];
            float4 av2 = alpha[i];
            us8 f2 = *(const us8*)&fsu[(size_t)sid2 * 256 + sub * 8];
            float a = (head == 0) ? av.x : (head == 1) ? av.y : (head == 2) ? av.z : av.w;
#pragma unroll
            for (int j = 0; j < 8; j++) acc[j] += a * bf2f(f[j]);
            av = av2; f = f2;
        }
        float a = (head == 0) ? av.x : (head == 1) ? av.y : (head == 2) ? av.z : av.w;
#pragma unroll
        for (int j = 0; j < 8; j++) acc[j] += a * bf2f(f[j]);
    }
    if (cnt & 1) {
        int e = s1 - 1;
        int sid = ssrc[e];
        float4 av = alpha[e];
        us8 f = *(const us8*)&fsu[(size_t)sid * 256 + sub * 8];
        float a = (head == 0) ? av.x : (head == 1) ? av.y : (head == 2) ? av.z : av.w;
        if (half) a = 0.f;
#pragma unroll
        for (int j = 0; j < 8; j++) acc[j] += a * bf2f(f[j]);
    }
#pragma unroll
    for (int j = 0; j < 8; j++) acc[j] += __shfl_xor(acc[j], 32);
    if (half == 0) {
        float4 b0 = *(const float4*)&b[sub * 8];
        float4 b1 = *(const float4*)&b[sub * 8 + 4];
        float4 o0 = make_float4(acc[0] + b0.x, acc[1] + b0.y, acc[2] + b0.z, acc[3] + b0.w);
        float4 o1 = make_float4(acc[4] + b1.x, acc[5] + b1.y, acc[6] + b1.z, acc[7] + b1.w);
        *(float4*)&rst[(size_t)n * 256 + sub * 8] = o0;
        *(float4*)&rst[(size_t)n * 256 + sub * 8 + 4] = o1;
    }
}

// generic aggregation (layer 2, D=47)
__global__ void agg_kernel(const bf16* __restrict__ fs, const float4* __restrict__ alpha,
                           const float* __restrict__ b,
                           const int* __restrict__ offs, const int* __restrict__ ssrc,
                           float* __restrict__ rst, int D, int nd)
{
    int wave = threadIdx.x >> 6, lane = threadIdx.x & 63;
    int n = blockIdx.x * 4 + wave;
    if (n >= nd) return;
    int HD = HEADS * D;
    bool act = (4 * lane) < HD;
    int h_[4];
#pragma unroll
    for (int j = 0; j < 4; j++) {
        int e = 4 * lane + j;
        h_[j] = (e < HD) ? (e / D) : 0;
    }
    float acc[4] = {0.f, 0.f, 0.f, 0.f};
    int s0 = offs[n], s1 = offs[n + 1];
    const unsigned short* fsu = (const unsigned short*)fs;
    for (int i = s0; i < s1; i++) {
        int sid = ssrc[i];
        float4 av = alpha[i];
        float a_[4] = {av.x, av.y, av.z, av.w};
        ushort4 f = {0, 0, 0, 0};
        if (act) f = *(const ushort4*)&fsu[(size_t)sid * HD + 4 * lane];
        unsigned short fa[4] = {f.x, f.y, f.z, f.w};
#pragma unroll
        for (int j = 0; j < 4; j++)
            acc[j] += a_[h_[j]] * bf2f(fa[j]);
    }
    if (act) {
#pragma unroll
        for (int j = 0; j < 4; j++) {
            int e4 = 4 * lane + j;
            rst[(size_t)n * HD + e4] = acc[j] + b[e4];
        }
    }
}

// ---------------- final layer ----------------
__global__ void final_kernel(const float* __restrict__ rst2, const float* __restrict__ h2,
                             const float* __restrict__ Ws, const float* __restrict__ bs,
                             float* __restrict__ out)
{
    const int K = 256, C = 47;
    int n = blockIdx.x;
    int c = threadIdx.x;
    float v = -INFINITY;
    if (c < C) {
        float dot = 0.f;
        for (int k = 0; k < K; k++) dot += h2[(size_t)n * K + k] * Ws[k * C + c];
        float mean = 0.f;
#pragma unroll
        for (int hh = 0; hh < HEADS; hh++) mean += rst2[(size_t)n * HEADS * C + hh * C + c];
        mean *= 0.25f;
        v = mean + dot + bs[c];
    }
    float mx = v;
    for (int off = 32; off; off >>= 1) mx = fmaxf(mx, __shfl_xor(mx, off));
    float ex = (c < C) ? __expf(v - mx) : 0.f;
    float sum = ex;
    for (int off = 32; off; off >>= 1) sum += __shfl_xor(sum, off);
    if (c < C) out[n * C + c] = v - mx - logf(sum);
}

extern "C" void kernel_launch(void* const* d_in, const int* in_sizes, int n_in,
                              void* d_out, int out_size, void* d_ws, size_t ws_size,
                              hipStream_t stream)
{
    const float* x = (const float*)d_in[0];
    const float* W[3]  = {(const float*)d_in[1],  (const float*)d_in[7],  (const float*)d_in[13]};
    const float* al[3] = {(const float*)d_in[2],  (const float*)d_in[8],  (const float*)d_in[14]};
    const float* ar[3] = {(const float*)d_in[3],  (const float*)d_in[9],  (const float*)d_in[15]};
    const float* bb[3] = {(const float*)d_in[4],  (const float*)d_in[10], (const float*)d_in[16]};
    const float* Ws[3] = {(const float*)d_in[5],  (const float*)d_in[11], (const float*)d_in[17]};
    const float* bs[3] = {(const float*)d_in[6],  (const float*)d_in[12], (const float*)d_in[18]};
    const int* srcp[3] = {(const int*)d_in[19], (const int*)d_in[21], (const int*)d_in[23]};
    const int* dstp[3] = {(const int*)d_in[20], (const int*)d_in[22], (const int*)d_in[24]};

    const int NS[3]  = {200000, 50000, 10000};
    const int ND[3]  = {50000, 10000, 2048};
    const int NEg[3] = {800000, 400000, 100000};
    const int CIN[3] = {128, 256, 256};
    const int DPH[3] = {64, 64, 47};

    char* p = (char*)d_ws;
    auto alloc = [&](size_t bytes) -> void* {
        void* r = (void*)p;
        p += (bytes + 255) & ~(size_t)255;
        return r;
    };
    bf16*  fsb  = (bf16*)alloc((size_t)200000 * 256 * 2);
    float* h1f  = (float*)alloc((size_t)50000 * 256 * 4);
    bf16*  h1b  = (bf16*)alloc((size_t)50000 * 256 * 2);
    float* h2f  = (float*)alloc((size_t)10000 * 256 * 4);
    bf16*  h2b  = (bf16*)alloc((size_t)10000 * 256 * 2);
    float* rst  = (float*)alloc((size_t)50000 * 256 * 4);
    float* elb  = (float*)alloc((size_t)200000 * 4 * 4);
    float* erb  = (float*)alloc((size_t)50000 * 4 * 4);
    float4* alpha = (float4*)alloc((size_t)800000 * 16);
    bf16*  Wt[3];  bf16* Wst[2];
    Wt[0]  = (bf16*)alloc(128 * 256 * 2);
    Wt[1]  = (bf16*)alloc(256 * 256 * 2);
    Wt[2]  = (bf16*)alloc(256 * 188 * 2);
    Wst[0] = (bf16*)alloc(128 * 256 * 2);
    Wst[1] = (bf16*)alloc(256 * 256 * 2);
    int* counts = (int*)alloc(50000 * 4);
    int* offs   = (int*)alloc(50001 * 4);
    int* cursor = (int*)alloc(50000 * 4);
    int* ssrc   = (int*)alloc(800000 * 4);
    int* bsum   = (int*)alloc(256 * 4);
    int* bpre   = (int*)alloc(256 * 4);

    {
        int sz;
        sz = 128 * 256; transpose_cast_kernel<<<(sz + 255) / 256, 256, 0, stream>>>(W[0],  Wt[0],  128, 256);
        sz = 256 * 256; transpose_cast_kernel<<<(sz + 255) / 256, 256, 0, stream>>>(W[1],  Wt[1],  256, 256);
        sz = 256 * 188; transpose_cast_kernel<<<(sz + 255) / 256, 256, 0, stream>>>(W[2],  Wt[2],  256, 188);
        sz = 128 * 256; transpose_cast_kernel<<<(sz + 255) / 256, 256, 0, stream>>>(Ws[0], Wst[0], 128, 256);
        sz = 256 * 256; transpose_cast_kernel<<<(sz + 255) / 256, 256, 0, stream>>>(Ws[1], Wst[1], 256, 256);
    }

    const void* hin = (const void*)x;   // layer 0: f32; layers 1,2: bf16
    float* hf[2] = {h1f, h2f};
    bf16*  hb[2] = {h1b, h2b};

    for (int l = 0; l < 3; l++) {
        int ns = NS[l], nd = ND[l], ne = NEg[l], cin = CIN[l], d = DPH[l];
        int hd = HEADS * d;

        // 1. fs = hin @ W
        dim3 g1((hd + 127) / 128, (ns + 127) / 128);
        if (l == 0)
            gemm_mfma<0, 1><<<g1, 256, 0, stream>>>(hin, Wt[l], nullptr, nullptr, fsb, nullptr, ns, hd, cin);
        else
            gemm_mfma<0, 0><<<g1, 256, 0, stream>>>(hin, Wt[l], nullptr, nullptr, fsb, nullptr, ns, hd, cin);

        // 2. attention logit halves
        if (d == 64)
            el_er64_kernel<<<1024, 256, 0, stream>>>(fsb, al[l], ar[l], elb, erb, ns, nd);
        else
            el_er_kernel<<<ns, 256, 0, stream>>>(fsb, al[l], ar[l], elb, erb, nd, d);

        // 3. CSR build (parallel 3-phase scan)
        int nb = (nd + 255) / 256;
        zero_int_kernel<<<256, 256, 0, stream>>>(counts, nd);
        hist_kernel<<<512, 256, 0, stream>>>(dstp[l], ne, counts);
        scan_a_kernel<<<nb, 256, 0, stream>>>(counts, bsum, nd);
        scan_b_kernel<<<1, 256, 0, stream>>>(bsum, bpre, offs, nb, nd);
        scan_c_kernel<<<nb, 256, 0, stream>>>(counts, bpre, offs, cursor, nd);
        scatter_kernel<<<512, 256, 0, stream>>>(srcp[l], dstp[l], ne, cursor, ssrc);

        // 4. normalized attention weights
        attn_kernel<<<(nd + 3) / 4, 256, 0, stream>>>(elb, erb, offs, ssrc, alpha, nd);

        // 5. aggregation
        if (d == 64)
            agg64_kernel<<<(nd + 3) / 4, 256, 0, stream>>>(fsb, alpha, bb[l], offs, ssrc, rst, nd);
        else
            agg_kernel<<<(nd + 3) / 4, 256, 0, stream>>>(fsb, alpha, bb[l], offs, ssrc, rst, d, nd);

        // 6. skip connection
        if (l < 2) {
            dim3 g2((256 + 127) / 128, (nd + 127) / 128);
            if (l == 0)
                gemm_mfma<1, 1><<<g2, 256, 0, stream>>>(hin, Wst[l], rst, bs[l], hb[l], hf[l], nd, 256, cin);
            else
                gemm_mfma<1, 0><<<g2, 256, 0, stream>>>(hin, Wst[l], rst, bs[l], hb[l], hf[l], nd, 256, cin);
            hin = (const void*)hb[l];
        } else {
            final_kernel<<<nd, 64, 0, stream>>>(rst, h2f, Ws[l], bs[l], (float*)d_out);
        }
    }
}

// Round 6
// 756.615 us; speedup vs baseline: 2.2728x; 1.1200x over previous
//
#include <hip/hip_runtime.h>
#include <hip/hip_bf16.h>
#include <cmath>

#define HEADS 4
typedef __hip_bfloat16 bf16;
typedef short short8 __attribute__((ext_vector_type(8)));
typedef unsigned short us8 __attribute__((ext_vector_type(8)));
typedef float floatx4 __attribute__((ext_vector_type(4)));

__device__ inline float bf2f(unsigned short u) {
    union { unsigned u; float f; } c; c.u = ((unsigned)u) << 16; return c.f;
}
__device__ inline short f2bs(float f) {
    bf16 h = __float2bfloat16(f);
    return *reinterpret_cast<short*>(&h);
}

// ---- problem constants (fixed shapes) ----
__device__ const int g_ND[3]   = {50000, 10000, 2048};
__device__ const int g_COFF[3] = {0, 50000, 60000};          // counts/cursor offsets
__device__ const int g_OOFF[3] = {0, 50001, 60002};          // offs offsets (nd+1 each)
__device__ const int g_NE[3]   = {800000, 400000, 100000};
__device__ const int g_SOFF[3] = {0, 800000, 1200000};
__device__ const int g_NB[3]   = {196, 40, 8};               // scan blocks per layer

// ---------------- all 5 weight transposes in one dispatch ----------------
__global__ void transpose_cast5(const float* __restrict__ W0, const float* __restrict__ W1,
                                const float* __restrict__ W2, const float* __restrict__ W3,
                                const float* __restrict__ W4,
                                bf16* __restrict__ B0, bf16* __restrict__ B1, bf16* __restrict__ B2,
                                bf16* __restrict__ B3, bf16* __restrict__ B4)
{
    const int Ks[5] = {128, 256, 256, 128, 256};
    const int Ns[5] = {256, 256, 188, 256, 256};
    int y = blockIdx.y;
    const float* W = (y == 0) ? W0 : (y == 1) ? W1 : (y == 2) ? W2 : (y == 3) ? W3 : W4;
    bf16* B = (y == 0) ? B0 : (y == 1) ? B1 : (y == 2) ? B2 : (y == 3) ? B3 : B4;
    int K = Ks[y], N = Ns[y], sz = K * N;
    for (int i = blockIdx.x * blockDim.x + threadIdx.x; i < sz; i += gridDim.x * blockDim.x) {
        int n = i / K, k = i % K;
        B[i] = __float2bfloat16(W[(size_t)k * N + n]);
    }
}

// ---------------- MFMA GEMM: C[M,N] = A[M,K] @ Bt[N,K]^T ----------------
// AF32: A is f32 (convert during staging). FUSE 1: Cb = bf16(elu(acc+add+bias)).
// EL 1 (requires N==256, heads of 64): fused el/er = C·al, C·ar per head.
template<int FUSE, int AF32, int EL>
__global__ __launch_bounds__(256)
void gemm_mfma(const void* __restrict__ Av, const bf16* __restrict__ Bt,
               const bf16* __restrict__ add, const float* __restrict__ bias,
               const float* __restrict__ al, const float* __restrict__ ar,
               float* __restrict__ el, float* __restrict__ er,
               bf16* __restrict__ Cb, int M, int N, int K, int nd)
{
    const int BM = 128, BN = 128, BK = 32;
    __shared__ short As[BM * BK];
    __shared__ short Bs[BN * BK];
    int tid = threadIdx.x;
    int wave = tid >> 6, lane = tid & 63;
    int q = lane >> 4, r = lane & 15;
    int row0 = blockIdx.y * BM, col0 = blockIdx.x * BN;
    int wm = (wave >> 1) * 64, wn = (wave & 1) * 64;
    int rrow = tid >> 2, chunk = tid & 3;

    const short* A16 = (const short*)Av;
    const float* Af  = (const float*)Av;
    const short* B16 = (const short*)Bt;

    // prefetch registers
    float4 pa0[2], pa1[2];
    short8 pa16[2];
    short8 pb[2];

    auto do_load = [&](int k0) {
#pragma unroll
        for (int rep = 0; rep < 2; rep++) {
            int rr = rrow + rep * 64;
            int grow = row0 + rr;
            if (AF32) {
                float4 z = {0.f, 0.f, 0.f, 0.f};
                pa0[rep] = z; pa1[rep] = z;
                if (grow < M) {
                    const float* pp = &Af[(size_t)grow * K + k0 + chunk * 8];
                    pa0[rep] = *(const float4*)pp;
                    pa1[rep] = *(const float4*)(pp + 4);
                }
            } else {
                short8 z = {0, 0, 0, 0, 0, 0, 0, 0};
                pa16[rep] = z;
                if (grow < M) pa16[rep] = *(const short8*)&A16[(size_t)grow * K + k0 + chunk * 8];
            }
            int gcol = col0 + rr;
            short8 zb = {0, 0, 0, 0, 0, 0, 0, 0};
            pb[rep] = zb;
            if (gcol < N) pb[rep] = *(const short8*)&B16[(size_t)gcol * K + k0 + chunk * 8];
        }
    };
    auto do_store = [&]() {
#pragma unroll
        for (int rep = 0; rep < 2; rep++) {
            int rr = rrow + rep * 64;
            short8 v;
            if (AF32) {
                v[0] = f2bs(pa0[rep].x); v[1] = f2bs(pa0[rep].y);
                v[2] = f2bs(pa0[rep].z); v[3] = f2bs(pa0[rep].w);
                v[4] = f2bs(pa1[rep].x); v[5] = f2bs(pa1[rep].y);
                v[6] = f2bs(pa1[rep].z); v[7] = f2bs(pa1[rep].w);
            } else v = pa16[rep];
            *(short8*)&As[rr * BK + chunk * 8] = v;
            *(short8*)&Bs[rr * BK + chunk * 8] = pb[rep];
        }
    };

    floatx4 zero = {0.f, 0.f, 0.f, 0.f};
    floatx4 acc[4][4];
#pragma unroll
    for (int i = 0; i < 4; i++)
#pragma unroll
        for (int j = 0; j < 4; j++) acc[i][j] = zero;

    do_load(0);
    do_store();
    __syncthreads();
    for (int k0 = 0; k0 < K; k0 += BK) {
        bool nxt = (k0 + BK) < K;
        if (nxt) do_load(k0 + BK);   // global loads overlap ds_read+MFMA below
        short8 af[4], bfr[4];
#pragma unroll
        for (int mt = 0; mt < 4; mt++) af[mt] = *(short8*)&As[(wm + mt * 16 + r) * BK + q * 8];
#pragma unroll
        for (int nt = 0; nt < 4; nt++) bfr[nt] = *(short8*)&Bs[(wn + nt * 16 + r) * BK + q * 8];
#pragma unroll
        for (int mt = 0; mt < 4; mt++)
#pragma unroll
            for (int nt = 0; nt < 4; nt++)
                acc[mt][nt] = __builtin_amdgcn_mfma_f32_16x16x32_bf16(af[mt], bfr[nt], acc[mt][nt], 0, 0, 0);
        if (nxt) {
            __syncthreads();
            do_store();
            __syncthreads();
        }
    }

    // C epilogue: D[row=q*4+e][col=r] per 16x16 tile
#pragma unroll
    for (int mt = 0; mt < 4; mt++) {
#pragma unroll
        for (int nt = 0; nt < 4; nt++) {
            int gcol = col0 + wn + nt * 16 + r;
            if (gcol >= N) continue;
#pragma unroll
            for (int e = 0; e < 4; e++) {
                int grow = row0 + wm + mt * 16 + q * 4 + e;
                if (grow >= M) continue;
                float v = acc[mt][nt][e];
                size_t idx = (size_t)grow * N + gcol;
                if (FUSE == 1) {
                    v += __bfloat162float(add[idx]) + bias[gcol];
                    v = (v > 0.f) ? v : (__expf(v) - 1.f);
                }
                Cb[idx] = __float2bfloat16(v);
            }
        }
    }

    // fused el/er: this wave's 64 cols == one head (N==256, BN=128)
    if (EL) {
        int head = (col0 + wn) >> 6;
        float alh[4], arh[4];
#pragma unroll
        for (int nt = 0; nt < 4; nt++) {
            int c = nt * 16 + r;
            alh[nt] = al[head * 64 + c];
            arh[nt] = ar[head * 64 + c];
        }
#pragma unroll
        for (int mt = 0; mt < 4; mt++) {
#pragma unroll
            for (int e = 0; e < 4; e++) {
                float pl = 0.f, pr = 0.f;
#pragma unroll
                for (int nt = 0; nt < 4; nt++) {
                    float v = acc[mt][nt][e];
                    pl += v * alh[nt];
                    pr += v * arh[nt];
                }
#pragma unroll
                for (int off = 1; off < 16; off <<= 1) {
                    pl += __shfl_xor(pl, off);
                    pr += __shfl_xor(pr, off);
                }
                int grow = row0 + wm + mt * 16 + q * 4 + e;
                if (r == 0 && grow < M) {
                    el[grow * 4 + head] = pl;
                    if (grow < nd) er[grow * 4 + head] = pr;
                }
            }
        }
    }
}

// ---------------- el/er generic (layer 2, D=47) ----------------
__global__ void el_er_kernel(const bf16* __restrict__ fs, const float* __restrict__ al,
                             const float* __restrict__ ar, float* __restrict__ el,
                             float* __restrict__ er, int nd, int D)
{
    int n = blockIdx.x;
    int h = threadIdx.x >> 6;
    int d = threadIdx.x & 63;
    int HD = HEADS * D;
    float v = 0.f, a = 0.f, rr = 0.f;
    if (d < D) {
        v = __bfloat162float(fs[(size_t)n * HD + h * D + d]);
        a = al[h * D + d];
        rr = ar[h * D + d];
    }
    float pl = v * a, pr = v * rr;
    for (int off = 32; off; off >>= 1) {
        pl += __shfl_down(pl, off);
        pr += __shfl_down(pr, off);
    }
    if (d == 0) {
        el[n * HEADS + h] = pl;
        if (n < nd) er[n * HEADS + h] = pr;
    }
}

// ---------------- CSR build (all 3 layers, merged) ----------------
__global__ void hist3_kernel(const int* __restrict__ d0, const int* __restrict__ d1,
                             const int* __restrict__ d2, int* __restrict__ cnt)
{
    for (int i = blockIdx.x * blockDim.x + threadIdx.x; i < 1300000; i += gridDim.x * blockDim.x) {
        int base, d;
        if (i < 800000)       { base = 0;     d = d0[i]; }
        else if (i < 1200000) { base = 50000; d = d1[i - 800000]; }
        else                  { base = 60000; d = d2[i - 1200000]; }
        atomicAdd(&cnt[base + d], 1);
    }
}

__global__ void scan_a3_kernel(const int* __restrict__ cnt, int* __restrict__ bsum)
{
    __shared__ int sdata[256];
    int l = blockIdx.y;
    if ((int)blockIdx.x >= g_NB[l]) return;
    int nd = g_ND[l], coff = g_COFF[l];
    int i = blockIdx.x * 256 + threadIdx.x;
    sdata[threadIdx.x] = (i < nd) ? cnt[coff + i] : 0;
    __syncthreads();
    for (int off = 128; off; off >>= 1) {
        if (threadIdx.x < off) sdata[threadIdx.x] += sdata[threadIdx.x + off];
        __syncthreads();
    }
    if (threadIdx.x == 0) bsum[l * 256 + blockIdx.x] = sdata[0];
}

__global__ void scan_b3_kernel(const int* __restrict__ bsum, int* __restrict__ bpre,
                               int* __restrict__ offs)
{
    __shared__ int sdata[256];
    int tid = threadIdx.x;
    for (int l = 0; l < 3; l++) {
        int v = (tid < g_NB[l]) ? bsum[l * 256 + tid] : 0;
        sdata[tid] = v;
        __syncthreads();
        for (int off = 1; off < 256; off <<= 1) {
            int t = (tid >= off) ? sdata[tid - off] : 0;
            __syncthreads();
            sdata[tid] += t;
            __syncthreads();
        }
        bpre[l * 256 + tid] = sdata[tid] - v;
        if (tid == 255) offs[g_OOFF[l] + g_ND[l]] = sdata[255];
        __syncthreads();
    }
}

__global__ void scan_c3_kernel(const int* __restrict__ cnt, const int* __restrict__ bpre,
                               int* __restrict__ offs, int* __restrict__ cursor)
{
    __shared__ int sdata[256];
    int l = blockIdx.y;
    if ((int)blockIdx.x >= g_NB[l]) return;
    int nd = g_ND[l], coff = g_COFF[l], ooff = g_OOFF[l];
    int tid = threadIdx.x;
    int i = blockIdx.x * 256 + tid;
    int v = (i < nd) ? cnt[coff + i] : 0;
    sdata[tid] = v;
    __syncthreads();
    for (int off = 1; off < 256; off <<= 1) {
        int t = (tid >= off) ? sdata[tid - off] : 0;
        __syncthreads();
        sdata[tid] += t;
        __syncthreads();
    }
    if (i < nd) {
        int e = bpre[l * 256 + blockIdx.x] + sdata[tid] - v;
        offs[ooff + i] = e;
        cursor[coff + i] = e;
    }
}

__global__ void scatter3_kernel(const int* __restrict__ s0, const int* __restrict__ d0,
                                const int* __restrict__ s1, const int* __restrict__ d1,
                                const int* __restrict__ s2, const int* __restrict__ d2,
                                int* __restrict__ cursor, int* __restrict__ ssrc)
{
    for (int i = blockIdx.x * blockDim.x + threadIdx.x; i < 1300000; i += gridDim.x * blockDim.x) {
        int base, soff, sv, dv;
        if (i < 800000)       { base = 0;     soff = 0;       sv = s0[i];           dv = d0[i]; }
        else if (i < 1200000) { base = 50000; soff = 800000;  sv = s1[i - 800000];  dv = d1[i - 800000]; }
        else                  { base = 60000; soff = 1200000; sv = s2[i - 1200000]; dv = d2[i - 1200000]; }
        int p = atomicAdd(&cursor[base + dv], 1);
        ssrc[soff + p] = sv;
    }
}

// ---------------- attention: 2-pass, writes UNNORMALIZED p (agg divides) ----------------
__global__ void attn_kernel(const float* __restrict__ el, const float* __restrict__ er,
                            const int* __restrict__ offs, const int* __restrict__ ssrc,
                            float4* __restrict__ alpha, int nd)
{
    int wave = threadIdx.x >> 6, lane = threadIdx.x & 63;
    int n = blockIdx.x * 4 + wave;
    if (n >= nd) return;
    int s0 = offs[n], s1 = offs[n + 1];
    float4 erv = *(const float4*)&er[(size_t)n * 4];

    float m0 = -INFINITY, m1 = -INFINITY, m2 = -INFINITY, m3 = -INFINITY;
    for (int i = s0 + lane; i < s1; i += 64) {
        int sid = ssrc[i];
        float4 ev = *(const float4*)&el[(size_t)sid * 4];
        float e0 = ev.x + erv.x; e0 = (e0 > 0.f) ? e0 : 0.2f * e0;
        float e1 = ev.y + erv.y; e1 = (e1 > 0.f) ? e1 : 0.2f * e1;
        float e2 = ev.z + erv.z; e2 = (e2 > 0.f) ? e2 : 0.2f * e2;
        float e3 = ev.w + erv.w; e3 = (e3 > 0.f) ? e3 : 0.2f * e3;
        alpha[i] = make_float4(e0, e1, e2, e3);
        m0 = fmaxf(m0, e0); m1 = fmaxf(m1, e1); m2 = fmaxf(m2, e2); m3 = fmaxf(m3, e3);
    }
#pragma unroll
    for (int off = 32; off; off >>= 1) {
        m0 = fmaxf(m0, __shfl_xor(m0, off));
        m1 = fmaxf(m1, __shfl_xor(m1, off));
        m2 = fmaxf(m2, __shfl_xor(m2, off));
        m3 = fmaxf(m3, __shfl_xor(m3, off));
    }
    for (int i = s0 + lane; i < s1; i += 64) {
        float4 e = alpha[i];
        alpha[i] = make_float4(__expf(e.x - m0), __expf(e.y - m1),
                               __expf(e.z - m2), __expf(e.w - m3));
    }
}

// ---------------- aggregation D=64 (HD=256): half-wave per edge, bf16 out ----------------
__global__ __launch_bounds__(256)
void agg64_kernel(const bf16* __restrict__ fs, const float4* __restrict__ alpha,
                  const float* __restrict__ b,
                  const int* __restrict__ offs, const int* __restrict__ ssrc,
                  bf16* __restrict__ rst, int nd)
{
    int wave = threadIdx.x >> 6, lane = threadIdx.x & 63;
    int n = blockIdx.x * 4 + wave;
    if (n >= nd) return;
    int half = lane >> 5, sub = lane & 31;
    int head = sub >> 3;
    int s0 = offs[n], s1 = offs[n + 1];
    int cnt = s1 - s0;
    const unsigned short* fsu = (const unsigned short*)fs;

    float acc[8];
#pragma unroll
    for (int j = 0; j < 8; j++) acc[j] = 0.f;
    float s = 0.f;

    int npairs = cnt >> 1;
    int i = s0 + half;
    if (npairs > 0) {
        int sid = ssrc[i];
        float4 av = alpha[i];
        us8 f = *(const us8*)&fsu[(size_t)sid * 256 + sub * 8];
        for (int p = 1; p < npairs; p++) {
            i += 2;
            int sid2 = ssrc[i];
            float4 av2 = alpha[i];
            us8 f2 = *(const us8*)&fsu[(size_t)sid2 * 256 + sub * 8];
            float a = (head == 0) ? av.x : (head == 1) ? av.y : (head == 2) ? av.z : av.w;
            s += a;
#pragma unroll
            for (int j = 0; j < 8; j++) acc[j] += a * bf2f(f[j]);
            av = av2; f = f2;
        }
        float a = (head == 0) ? av.x : (head == 1) ? av.y : (head == 2) ? av.z : av.w;
        s += a;
#pragma unroll
        for (int j = 0; j < 8; j++) acc[j] += a * bf2f(f[j]);
    }
    if (cnt & 1) {
        int e = s1 - 1;
        int sid = ssrc[e];
        float4 av = alpha[e];
        us8 f = *(const us8*)&fsu[(size_t)sid * 256 + sub * 8];
        float a = (head == 0) ? av.x : (head == 1) ? av.y : (head == 2) ? av.z : av.w;
        if (half) a = 0.f;
        s += a;
#pragma unroll
        for (int j = 0; j < 8; j++) acc[j] += a * bf2f(f[j]);
    }
    s += __shfl_xor(s, 32);
#pragma unroll
    for (int j = 0; j < 8; j++) acc[j] += __shfl_xor(acc[j], 32);
    if (half == 0) {
        float inv = (s > 0.f) ? 1.f / s : 0.f;
        float4 b0 = *(const float4*)&b[sub * 8];
        float4 b1 = *(const float4*)&b[sub * 8 + 4];
        us8 o;
        o[0] = (unsigned short)f2bs(acc[0] * inv + b0.x);
        o[1] = (unsigned short)f2bs(acc[1] * inv + b0.y);
        o[2] = (unsigned short)f2bs(acc[2] * inv + b0.z);
        o[3] = (unsigned short)f2bs(acc[3] * inv + b0.w);
        o[4] = (unsigned short)f2bs(acc[4] * inv + b1.x);
        o[5] = (unsigned short)f2bs(acc[5] * inv + b1.y);
        o[6] = (unsigned short)f2bs(acc[6] * inv + b1.z);
        o[7] = (unsigned short)f2bs(acc[7] * inv + b1.w);
        *(us8*)&((unsigned short*)rst)[(size_t)n * 256 + sub * 8] = o;
    }
}

// generic aggregation (layer 2, D=47), bf16 out
__global__ void agg_kernel(const bf16* __restrict__ fs, const float4* __restrict__ alpha,
                           const float* __restrict__ b,
                           const int* __restrict__ offs, const int* __restrict__ ssrc,
                           bf16* __restrict__ rst, int D, int nd)
{
    int wave = threadIdx.x >> 6, lane = threadIdx.x & 63;
    int n = blockIdx.x * 4 + wave;
    if (n >= nd) return;
    int HD = HEADS * D;
    bool act = (4 * lane) < HD;
    int h_[4];
#pragma unroll
    for (int j = 0; j < 4; j++) {
        int e = 4 * lane + j;
        h_[j] = (e < HD) ? (e / D) : 0;
    }
    float acc[4] = {0.f, 0.f, 0.f, 0.f};
    float s_[4] = {0.f, 0.f, 0.f, 0.f};
    int s0 = offs[n], s1 = offs[n + 1];
    const unsigned short* fsu = (const unsigned short*)fs;
    for (int i = s0; i < s1; i++) {
        int sid = ssrc[i];
        float4 av = alpha[i];
        float a_[4] = {av.x, av.y, av.z, av.w};
        ushort4 f = {0, 0, 0, 0};
        if (act) f = *(const ushort4*)&fsu[(size_t)sid * HD + 4 * lane];
        unsigned short fa[4] = {f.x, f.y, f.z, f.w};
#pragma unroll
        for (int j = 0; j < 4; j++) {
            float a = a_[h_[j]];
            s_[j] += a;
            acc[j] += a * bf2f(fa[j]);
        }
    }
    if (act) {
#pragma unroll
        for (int j = 0; j < 4; j++) {
            int e4 = 4 * lane + j;
            float o = (s_[j] > 0.f) ? acc[j] / s_[j] : 0.f;
            rst[(size_t)n * HD + e4] = __float2bfloat16(o + b[e4]);
        }
    }
}

// ---------------- final layer ----------------
__global__ void final_kernel(const bf16* __restrict__ rst2, const bf16* __restrict__ h2,
                             const float* __restrict__ Ws, const float* __restrict__ bs,
                             float* __restrict__ out)
{
    const int K = 256, C = 47;
    int n = blockIdx.x;
    int c = threadIdx.x;
    float v = -INFINITY;
    if (c < C) {
        float dot = 0.f;
        for (int k = 0; k < K; k++) dot += __bfloat162float(h2[(size_t)n * K + k]) * Ws[k * C + c];
        float mean = 0.f;
#pragma unroll
        for (int hh = 0; hh < HEADS; hh++) mean += __bfloat162float(rst2[(size_t)n * HEADS * C + hh * C + c]);
        mean *= 0.25f;
        v = mean + dot + bs[c];
    }
    float mx = v;
    for (int off = 32; off; off >>= 1) mx = fmaxf(mx, __shfl_xor(mx, off));
    float ex = (c < C) ? __expf(v - mx) : 0.f;
    float sum = ex;
    for (int off = 32; off; off >>= 1) sum += __shfl_xor(sum, off);
    if (c < C) out[n * C + c] = v - mx - logf(sum);
}

extern "C" void kernel_launch(void* const* d_in, const int* in_sizes, int n_in,
                              void* d_out, int out_size, void* d_ws, size_t ws_size,
                              hipStream_t stream)
{
    const float* x = (const float*)d_in[0];
    const float* W[3]  = {(const float*)d_in[1],  (const float*)d_in[7],  (const float*)d_in[13]};
    const float* al[3] = {(const float*)d_in[2],  (const float*)d_in[8],  (const float*)d_in[14]};
    const float* ar[3] = {(const float*)d_in[3],  (const float*)d_in[9],  (const float*)d_in[15]};
    const float* bb[3] = {(const float*)d_in[4],  (const float*)d_in[10], (const float*)d_in[16]};
    const float* Ws[3] = {(const float*)d_in[5],  (const float*)d_in[11], (const float*)d_in[17]};
    const float* bs[3] = {(const float*)d_in[6],  (const float*)d_in[12], (const float*)d_in[18]};
    const int* srcp[3] = {(const int*)d_in[19], (const int*)d_in[21], (const int*)d_in[23]};
    const int* dstp[3] = {(const int*)d_in[20], (const int*)d_in[22], (const int*)d_in[24]};

    char* p = (char*)d_ws;
    auto alloc = [&](size_t bytes) -> void* {
        void* r = (void*)p;
        p += (bytes + 255) & ~(size_t)255;
        return r;
    };
    bf16*  fsb   = (bf16*)alloc((size_t)200000 * 256 * 2);
    bf16*  h1b   = (bf16*)alloc((size_t)50000 * 256 * 2);
    bf16*  h2b   = (bf16*)alloc((size_t)10000 * 256 * 2);
    bf16*  rstb  = (bf16*)alloc((size_t)50000 * 256 * 2);
    float* elb   = (float*)alloc((size_t)200000 * 4 * 4);
    float* erb   = (float*)alloc((size_t)50000 * 4 * 4);
    float4* alpha = (float4*)alloc((size_t)800000 * 16);
    bf16* Wt[3]; bf16* Wst[2];
    Wt[0]  = (bf16*)alloc(128 * 256 * 2);
    Wt[1]  = (bf16*)alloc(256 * 256 * 2);
    Wt[2]  = (bf16*)alloc(256 * 188 * 2);
    Wst[0] = (bf16*)alloc(128 * 256 * 2);
    Wst[1] = (bf16*)alloc(256 * 256 * 2);
    int* counts   = (int*)alloc(62048 * 4);
    int* offs_all = (int*)alloc(62051 * 4);
    int* cursor   = (int*)alloc(62048 * 4);
    int* ssrc_all = (int*)alloc(1300000 * 4);
    int* bsum     = (int*)alloc(768 * 4);
    int* bpre     = (int*)alloc(768 * 4);

    const int OOFF[3] = {0, 50001, 60002};
    const int SOFF[3] = {0, 800000, 1200000};

    // weights (1 dispatch)
    transpose_cast5<<<dim3(64, 5), 256, 0, stream>>>(W[0], W[1], W[2], Ws[0], Ws[1],
                                                     Wt[0], Wt[1], Wt[2], Wst[0], Wst[1]);

    // CSR for all 3 layers up-front (graph-topology only)
    hipMemsetAsync(counts, 0, 62048 * 4, stream);
    hist3_kernel<<<512, 256, 0, stream>>>(dstp[0], dstp[1], dstp[2], counts);
    scan_a3_kernel<<<dim3(196, 3), 256, 0, stream>>>(counts, bsum);
    scan_b3_kernel<<<1, 256, 0, stream>>>(bsum, bpre, offs_all);
    scan_c3_kernel<<<dim3(196, 3), 256, 0, stream>>>(counts, bpre, offs_all, cursor);
    scatter3_kernel<<<512, 256, 0, stream>>>(srcp[0], dstp[0], srcp[1], dstp[1], srcp[2], dstp[2],
                                             cursor, ssrc_all);

    // ---- layer 0 (D=64, cin=128, A=f32 x) ----
    gemm_mfma<0, 1, 1><<<dim3(2, 1563), 256, 0, stream>>>(
        x, Wt[0], nullptr, nullptr, al[0], ar[0], elb, erb, fsb, 200000, 256, 128, 50000);
    attn_kernel<<<12500, 256, 0, stream>>>(elb, erb, offs_all + OOFF[0], ssrc_all + SOFF[0], alpha, 50000);
    agg64_kernel<<<12500, 256, 0, stream>>>(fsb, alpha, bb[0], offs_all + OOFF[0], ssrc_all + SOFF[0], rstb, 50000);
    gemm_mfma<1, 1, 0><<<dim3(2, 391), 256, 0, stream>>>(
        x, Wst[0], rstb, bs[0], nullptr, nullptr, nullptr, nullptr, h1b, 50000, 256, 128, 0);

    // ---- layer 1 (D=64, cin=256, A=bf16 h1) ----
    gemm_mfma<0, 0, 1><<<dim3(2, 391), 256, 0, stream>>>(
        h1b, Wt[1], nullptr, nullptr, al[1], ar[1], elb, erb, fsb, 50000, 256, 256, 10000);
    attn_kernel<<<2500, 256, 0, stream>>>(elb, erb, offs_all + OOFF[1], ssrc_all + SOFF[1], alpha, 10000);
    agg64_kernel<<<2500, 256, 0, stream>>>(fsb, alpha, bb[1], offs_all + OOFF[1], ssrc_all + SOFF[1], rstb, 10000);
    gemm_mfma<1, 0, 0><<<dim3(2, 79), 256, 0, stream>>>(
        h1b, Wst[1], rstb, bs[1], nullptr, nullptr, nullptr, nullptr, h2b, 10000, 256, 256, 0);

    // ---- layer 2 (D=47, cin=256, A=bf16 h2) ----
    gemm_mfma<0, 0, 0><<<dim3(2, 79), 256, 0, stream>>>(
        h2b, Wt[2], nullptr, nullptr, nullptr, nullptr, nullptr, nullptr, fsb, 10000, 188, 256, 0);
    el_er_kernel<<<10000, 256, 0, stream>>>(fsb, al[2], ar[2], elb, erb, 2048, 47);
    attn_kernel<<<512, 256, 0, stream>>>(elb, erb, offs_all + OOFF[2], ssrc_all + SOFF[2], alpha, 2048);
    agg_kernel<<<512, 256, 0, stream>>>(fsb, alpha, bb[2], offs_all + OOFF[2], ssrc_all + SOFF[2], rstb, 47, 2048);
    final_kernel<<<2048, 64, 0, stream>>>(rstb, h2b, Ws[2], bs[2], (float*)d_out);
}

// Round 7
// 703.938 us; speedup vs baseline: 2.4429x; 1.0748x over previous
//
#include <hip/hip_runtime.h>
#include <hip/hip_bf16.h>
#include <cmath>

#define HEADS 4
typedef __hip_bfloat16 bf16;
typedef short short8 __attribute__((ext_vector_type(8)));
typedef unsigned short us8 __attribute__((ext_vector_type(8)));
typedef float floatx4 __attribute__((ext_vector_type(4)));
typedef unsigned int u32;

__device__ inline float bf2f(unsigned short u) {
    union { unsigned u; float f; } c; c.u = ((unsigned)u) << 16; return c.f;
}
__device__ inline short f2bs(float f) {
    bf16 h = __float2bfloat16(f);
    return *reinterpret_cast<short*>(&h);
}

// async 16B global->LDS (DMA, no VGPR round-trip). LDS dest: wave-uniform base + lane*16.
__device__ __forceinline__ void ld_lds16(const void* g, void* l) {
    __builtin_amdgcn_global_load_lds((const __attribute__((address_space(1))) u32*)g,
                                     (__attribute__((address_space(3))) u32*)l, 16, 0, 0);
}

// ---- problem constants ----
__device__ const int g_ND[3]   = {50000, 10000, 2048};
__device__ const int g_COFF[3] = {0, 50000, 60000};
__device__ const int g_OOFF[3] = {0, 50001, 60002};
__device__ const int g_NB[3]   = {196, 40, 8};

// ---------------- weights transpose-cast (5 slabs) + x cast, one dispatch ----------------
__global__ void precast_all(const float* __restrict__ W0, const float* __restrict__ W1,
                            const float* __restrict__ W2, const float* __restrict__ W3,
                            const float* __restrict__ W4, const float* __restrict__ x,
                            bf16* __restrict__ B0, bf16* __restrict__ B1, bf16* __restrict__ B2,
                            bf16* __restrict__ B3, bf16* __restrict__ B4, bf16* __restrict__ xb)
{
    int y = blockIdx.y;
    if (y == 5) {
        const float4* in = (const float4*)x;
        ushort4* out = (ushort4*)xb;
        const int n4 = 200000 * 128 / 4;
        for (int i = blockIdx.x * blockDim.x + threadIdx.x; i < n4; i += gridDim.x * blockDim.x) {
            float4 v = in[i];
            ushort4 o;
            o.x = (unsigned short)f2bs(v.x); o.y = (unsigned short)f2bs(v.y);
            o.z = (unsigned short)f2bs(v.z); o.w = (unsigned short)f2bs(v.w);
            out[i] = o;
        }
        return;
    }
    const int Ks[5] = {128, 256, 256, 128, 256};
    const int Ns[5] = {256, 256, 188, 256, 256};
    const float* W = (y == 0) ? W0 : (y == 1) ? W1 : (y == 2) ? W2 : (y == 3) ? W3 : W4;
    bf16* B = (y == 0) ? B0 : (y == 1) ? B1 : (y == 2) ? B2 : (y == 3) ? B3 : B4;
    int K = Ks[y], N = Ns[y], sz = K * N;
    for (int i = blockIdx.x * blockDim.x + threadIdx.x; i < sz; i += gridDim.x * blockDim.x) {
        int n = i / K, k = i % K;
        B[i] = __float2bfloat16(W[(size_t)k * N + n]);
    }
}

// ---------------- MFMA GEMM: C[M,N] = A[M,K] @ Bt[N,K]^T (all bf16 inputs) ----------------
// A must be padded to grid-y*128 rows, Bt to grid-x*128 rows. K multiple of 32.
// FUSE 1: Cb = bf16(elu(acc+add+bias)). EL 1 (N==256): fused el/er per head.
template<int FUSE, int EL>
__global__ __launch_bounds__(256)
void gemm_mfma(const bf16* __restrict__ A, const bf16* __restrict__ Bt,
               const bf16* __restrict__ add, const float* __restrict__ bias,
               const float* __restrict__ al, const float* __restrict__ ar,
               float* __restrict__ el, float* __restrict__ er,
               bf16* __restrict__ Cb, int M, int N, int K, int nd)
{
    const int BM = 128, BN = 128, BK = 32;
    __shared__ short As[BM * BK];
    __shared__ short Bs[BN * BK];
    int tid = threadIdx.x;
    int wave = tid >> 6, lane = tid & 63;
    int q = lane >> 4, r = lane & 15;
    int row0 = blockIdx.y * BM, col0 = blockIdx.x * BN;
    int wm = (wave >> 1) * 64, wn = (wave & 1) * 64;

    const short* A16 = (const short*)A;
    const short* B16 = (const short*)Bt;
    const short* ga0 = A16 + (size_t)(row0 + (tid >> 2)) * K + (tid & 3) * 8;
    const short* ga1 = ga0 + (size_t)64 * K;
    const short* gb0 = B16 + (size_t)(col0 + (tid >> 2)) * K + (tid & 3) * 8;
    const short* gb1 = gb0 + (size_t)64 * K;
    char* la0 = (char*)As + tid * 16;
    char* la1 = la0 + 4096;
    char* lb0 = (char*)Bs + tid * 16;
    char* lb1 = lb0 + 4096;

    floatx4 zero = {0.f, 0.f, 0.f, 0.f};
    floatx4 acc[4][4];
#pragma unroll
    for (int i = 0; i < 4; i++)
#pragma unroll
        for (int j = 0; j < 4; j++) acc[i][j] = zero;

    for (int k0 = 0; k0 < K; k0 += BK) {
        ld_lds16(ga0, la0); ld_lds16(ga1, la1);
        ld_lds16(gb0, lb0); ld_lds16(gb1, lb1);
        ga0 += BK; ga1 += BK; gb0 += BK; gb1 += BK;
        __syncthreads();   // drains vmcnt (async LDS loads) before use
        short8 af[4], bfr[4];
#pragma unroll
        for (int mt = 0; mt < 4; mt++) af[mt] = *(short8*)&As[(wm + mt * 16 + r) * BK + q * 8];
#pragma unroll
        for (int nt = 0; nt < 4; nt++) bfr[nt] = *(short8*)&Bs[(wn + nt * 16 + r) * BK + q * 8];
#pragma unroll
        for (int mt = 0; mt < 4; mt++)
#pragma unroll
            for (int nt = 0; nt < 4; nt++)
                acc[mt][nt] = __builtin_amdgcn_mfma_f32_16x16x32_bf16(af[mt], bfr[nt], acc[mt][nt], 0, 0, 0);
        __syncthreads();   // protect LDS before next iteration's staging
    }

    // C epilogue: D[row=q*4+e][col=r] per 16x16 tile
#pragma unroll
    for (int mt = 0; mt < 4; mt++) {
#pragma unroll
        for (int nt = 0; nt < 4; nt++) {
            int gcol = col0 + wn + nt * 16 + r;
            if (gcol >= N) continue;
#pragma unroll
            for (int e = 0; e < 4; e++) {
                int grow = row0 + wm + mt * 16 + q * 4 + e;
                if (grow >= M) continue;
                float v = acc[mt][nt][e];
                size_t idx = (size_t)grow * N + gcol;
                if (FUSE == 1) {
                    v += __bfloat162float(add[idx]) + bias[gcol];
                    v = (v > 0.f) ? v : (__expf(v) - 1.f);
                }
                Cb[idx] = __float2bfloat16(v);
            }
        }
    }

    // fused el/er: this wave's 64 cols == one head (requires N==256)
    if (EL) {
        int head = (col0 + wn) >> 6;
        float alh[4], arh[4];
#pragma unroll
        for (int nt = 0; nt < 4; nt++) {
            int c = nt * 16 + r;
            alh[nt] = al[head * 64 + c];
            arh[nt] = ar[head * 64 + c];
        }
#pragma unroll
        for (int mt = 0; mt < 4; mt++) {
#pragma unroll
            for (int e = 0; e < 4; e++) {
                float pl = 0.f, pr = 0.f;
#pragma unroll
                for (int nt = 0; nt < 4; nt++) {
                    float v = acc[mt][nt][e];
                    pl += v * alh[nt];
                    pr += v * arh[nt];
                }
#pragma unroll
                for (int off = 1; off < 16; off <<= 1) {
                    pl += __shfl_xor(pl, off);
                    pr += __shfl_xor(pr, off);
                }
                int grow = row0 + wm + mt * 16 + q * 4 + e;
                if (r == 0 && grow < M) {
                    el[grow * 4 + head] = pl;
                    if (grow < nd) er[grow * 4 + head] = pr;
                }
            }
        }
    }
}

// ---------------- el/er generic (layer 2, D=47) ----------------
__global__ void el_er_kernel(const bf16* __restrict__ fs, const float* __restrict__ al,
                             const float* __restrict__ ar, float* __restrict__ el,
                             float* __restrict__ er, int nd, int D)
{
    int n = blockIdx.x;
    int h = threadIdx.x >> 6;
    int d = threadIdx.x & 63;
    int HD = HEADS * D;
    float v = 0.f, a = 0.f, rr = 0.f;
    if (d < D) {
        v = __bfloat162float(fs[(size_t)n * HD + h * D + d]);
        a = al[h * D + d];
        rr = ar[h * D + d];
    }
    float pl = v * a, pr = v * rr;
    for (int off = 32; off; off >>= 1) {
        pl += __shfl_down(pl, off);
        pr += __shfl_down(pr, off);
    }
    if (d == 0) {
        el[n * HEADS + h] = pl;
        if (n < nd) er[n * HEADS + h] = pr;
    }
}

// ---------------- CSR build (all 3 layers) ----------------
__global__ void hist3_kernel(const int* __restrict__ d0, const int* __restrict__ d1,
                             const int* __restrict__ d2, int* __restrict__ cnt)
{
    for (int i = blockIdx.x * blockDim.x + threadIdx.x; i < 1300000; i += gridDim.x * blockDim.x) {
        int base, d;
        if (i < 800000)       { base = 0;     d = d0[i]; }
        else if (i < 1200000) { base = 50000; d = d1[i - 800000]; }
        else                  { base = 60000; d = d2[i - 1200000]; }
        atomicAdd(&cnt[base + d], 1);
    }
}

__global__ void scan_a3_kernel(const int* __restrict__ cnt, int* __restrict__ bsum)
{
    __shared__ int sdata[256];
    int l = blockIdx.y;
    if ((int)blockIdx.x >= g_NB[l]) return;
    int nd = g_ND[l], coff = g_COFF[l];
    int i = blockIdx.x * 256 + threadIdx.x;
    sdata[threadIdx.x] = (i < nd) ? cnt[coff + i] : 0;
    __syncthreads();
    for (int off = 128; off; off >>= 1) {
        if (threadIdx.x < off) sdata[threadIdx.x] += sdata[threadIdx.x + off];
        __syncthreads();
    }
    if (threadIdx.x == 0) bsum[l * 256 + blockIdx.x] = sdata[0];
}

__global__ void scan_b3_kernel(const int* __restrict__ bsum, int* __restrict__ bpre,
                               int* __restrict__ offs)
{
    __shared__ int sdata[256];
    int tid = threadIdx.x;
    for (int l = 0; l < 3; l++) {
        int v = (tid < g_NB[l]) ? bsum[l * 256 + tid] : 0;
        sdata[tid] = v;
        __syncthreads();
        for (int off = 1; off < 256; off <<= 1) {
            int t = (tid >= off) ? sdata[tid - off] : 0;
            __syncthreads();
            sdata[tid] += t;
            __syncthreads();
        }
        bpre[l * 256 + tid] = sdata[tid] - v;
        if (tid == 255) offs[g_OOFF[l] + g_ND[l]] = sdata[255];
        __syncthreads();
    }
}

__global__ void scan_c3_kernel(const int* __restrict__ cnt, const int* __restrict__ bpre,
                               int* __restrict__ offs, int* __restrict__ cursor)
{
    __shared__ int sdata[256];
    int l = blockIdx.y;
    if ((int)blockIdx.x >= g_NB[l]) return;
    int nd = g_ND[l], coff = g_COFF[l], ooff = g_OOFF[l];
    int tid = threadIdx.x;
    int i = blockIdx.x * 256 + tid;
    int v = (i < nd) ? cnt[coff + i] : 0;
    sdata[tid] = v;
    __syncthreads();
    for (int off = 1; off < 256; off <<= 1) {
        int t = (tid >= off) ? sdata[tid - off] : 0;
        __syncthreads();
        sdata[tid] += t;
        __syncthreads();
    }
    if (i < nd) {
        int e = bpre[l * 256 + blockIdx.x] + sdata[tid] - v;
        offs[ooff + i] = e;
        cursor[coff + i] = e;
    }
}

__global__ void scatter3_kernel(const int* __restrict__ s0, const int* __restrict__ d0,
                                const int* __restrict__ s1, const int* __restrict__ d1,
                                const int* __restrict__ s2, const int* __restrict__ d2,
                                int* __restrict__ cursor, int* __restrict__ ssrc)
{
    for (int i = blockIdx.x * blockDim.x + threadIdx.x; i < 1300000; i += gridDim.x * blockDim.x) {
        int base, soff, sv, dv;
        if (i < 800000)       { base = 0;     soff = 0;       sv = s0[i];           dv = d0[i]; }
        else if (i < 1200000) { base = 50000; soff = 800000;  sv = s1[i - 800000];  dv = d1[i - 800000]; }
        else                  { base = 60000; soff = 1200000; sv = s2[i - 1200000]; dv = d2[i - 1200000]; }
        int p = atomicAdd(&cursor[base + dv], 1);
        ssrc[soff + p] = sv;
    }
}

// ---------------- fused attention+aggregation, D=64 (HD=256) ----------------
// phase 1: per-head max (lanes over edges). phase 2: half-wave per edge, exp inline.
__global__ __launch_bounds__(256)
void attn_agg64(const bf16* __restrict__ fs, const float* __restrict__ el,
                const float* __restrict__ er, const float* __restrict__ b,
                const int* __restrict__ offs, const int* __restrict__ ssrc,
                bf16* __restrict__ rst, int nd)
{
    int wave = threadIdx.x >> 6, lane = threadIdx.x & 63;
    int n = blockIdx.x * 4 + wave;
    if (n >= nd) return;
    int s0 = offs[n], s1 = offs[n + 1];
    float4 erv = *(const float4*)&er[(size_t)n * 4];

    float m0 = -INFINITY, m1 = -INFINITY, m2 = -INFINITY, m3 = -INFINITY;
    for (int i = s0 + lane; i < s1; i += 64) {
        int sid = ssrc[i];
        float4 ev = *(const float4*)&el[(size_t)sid * 4];
        float e0 = ev.x + erv.x; e0 = (e0 > 0.f) ? e0 : 0.2f * e0;
        float e1 = ev.y + erv.y; e1 = (e1 > 0.f) ? e1 : 0.2f * e1;
        float e2 = ev.z + erv.z; e2 = (e2 > 0.f) ? e2 : 0.2f * e2;
        float e3 = ev.w + erv.w; e3 = (e3 > 0.f) ? e3 : 0.2f * e3;
        m0 = fmaxf(m0, e0); m1 = fmaxf(m1, e1); m2 = fmaxf(m2, e2); m3 = fmaxf(m3, e3);
    }
#pragma unroll
    for (int off = 32; off; off >>= 1) {
        m0 = fmaxf(m0, __shfl_xor(m0, off));
        m1 = fmaxf(m1, __shfl_xor(m1, off));
        m2 = fmaxf(m2, __shfl_xor(m2, off));
        m3 = fmaxf(m3, __shfl_xor(m3, off));
    }

    int half = lane >> 5, sub = lane & 31, head = sub >> 3;
    float mh  = (head == 0) ? m0 : (head == 1) ? m1 : (head == 2) ? m2 : m3;
    float eh  = (head == 0) ? erv.x : (head == 1) ? erv.y : (head == 2) ? erv.z : erv.w;
    const unsigned short* fsu = (const unsigned short*)fs;

    float acc[8];
#pragma unroll
    for (int j = 0; j < 8; j++) acc[j] = 0.f;
    float s = 0.f;

    int cnt = s1 - s0;
    int npairs = cnt >> 1;
    int i = s0 + half;
    if (npairs > 0) {
        int sid = ssrc[i];
        float ev = el[(size_t)sid * 4 + head];
        us8 f = *(const us8*)&fsu[(size_t)sid * 256 + sub * 8];
        for (int p = 1; p < npairs; p++) {
            i += 2;
            int sid2 = ssrc[i];
            float ev2 = el[(size_t)sid2 * 4 + head];
            us8 f2 = *(const us8*)&fsu[(size_t)sid2 * 256 + sub * 8];
            float e = ev + eh; e = (e > 0.f) ? e : 0.2f * e;
            float a = __expf(e - mh);
            s += a;
#pragma unroll
            for (int j = 0; j < 8; j++) acc[j] += a * bf2f(f[j]);
            ev = ev2; f = f2;
        }
        float e = ev + eh; e = (e > 0.f) ? e : 0.2f * e;
        float a = __expf(e - mh);
        s += a;
#pragma unroll
        for (int j = 0; j < 8; j++) acc[j] += a * bf2f(f[j]);
    }
    if (cnt & 1) {
        int idx = s1 - 1;
        int sid = ssrc[idx];
        float ev = el[(size_t)sid * 4 + head];
        us8 f = *(const us8*)&fsu[(size_t)sid * 256 + sub * 8];
        float e = ev + eh; e = (e > 0.f) ? e : 0.2f * e;
        float a = __expf(e - mh);
        if (half) a = 0.f;
        s += a;
#pragma unroll
        for (int j = 0; j < 8; j++) acc[j] += a * bf2f(f[j]);
    }
    s += __shfl_xor(s, 32);
#pragma unroll
    for (int j = 0; j < 8; j++) acc[j] += __shfl_xor(acc[j], 32);
    if (half == 0) {
        float inv = (s > 0.f) ? 1.f / s : 0.f;
        float4 b0 = *(const float4*)&b[sub * 8];
        float4 b1 = *(const float4*)&b[sub * 8 + 4];
        us8 o;
        o[0] = (unsigned short)f2bs(acc[0] * inv + b0.x);
        o[1] = (unsigned short)f2bs(acc[1] * inv + b0.y);
        o[2] = (unsigned short)f2bs(acc[2] * inv + b0.z);
        o[3] = (unsigned short)f2bs(acc[3] * inv + b0.w);
        o[4] = (unsigned short)f2bs(acc[4] * inv + b1.x);
        o[5] = (unsigned short)f2bs(acc[5] * inv + b1.y);
        o[6] = (unsigned short)f2bs(acc[6] * inv + b1.z);
        o[7] = (unsigned short)f2bs(acc[7] * inv + b1.w);
        *(us8*)&((unsigned short*)rst)[(size_t)n * 256 + sub * 8] = o;
    }
}

// ---------------- fused attention+aggregation generic (layer 2, D=47) ----------------
__global__ void attn_agg_gen(const bf16* __restrict__ fs, const float* __restrict__ el,
                             const float* __restrict__ er, const float* __restrict__ b,
                             const int* __restrict__ offs, const int* __restrict__ ssrc,
                             bf16* __restrict__ rst, int D, int nd)
{
    int wave = threadIdx.x >> 6, lane = threadIdx.x & 63;
    int n = blockIdx.x * 4 + wave;
    if (n >= nd) return;
    int HD = HEADS * D;
    int s0 = offs[n], s1 = offs[n + 1];
    float4 erv = *(const float4*)&er[(size_t)n * 4];

    float m0 = -INFINITY, m1 = -INFINITY, m2 = -INFINITY, m3 = -INFINITY;
    for (int i = s0 + lane; i < s1; i += 64) {
        int sid = ssrc[i];
        float4 ev = *(const float4*)&el[(size_t)sid * 4];
        float e0 = ev.x + erv.x; e0 = (e0 > 0.f) ? e0 : 0.2f * e0;
        float e1 = ev.y + erv.y; e1 = (e1 > 0.f) ? e1 : 0.2f * e1;
        float e2 = ev.z + erv.z; e2 = (e2 > 0.f) ? e2 : 0.2f * e2;
        float e3 = ev.w + erv.w; e3 = (e3 > 0.f) ? e3 : 0.2f * e3;
        m0 = fmaxf(m0, e0); m1 = fmaxf(m1, e1); m2 = fmaxf(m2, e2); m3 = fmaxf(m3, e3);
    }
#pragma unroll
    for (int off = 32; off; off >>= 1) {
        m0 = fmaxf(m0, __shfl_xor(m0, off));
        m1 = fmaxf(m1, __shfl_xor(m1, off));
        m2 = fmaxf(m2, __shfl_xor(m2, off));
        m3 = fmaxf(m3, __shfl_xor(m3, off));
    }

    bool act = (4 * lane) < HD;
    int h_[4];
#pragma unroll
    for (int j = 0; j < 4; j++) {
        int e = 4 * lane + j;
        h_[j] = (e < HD) ? (e / D) : 0;
    }
    float acc[4] = {0.f, 0.f, 0.f, 0.f};
    float sh[4] = {0.f, 0.f, 0.f, 0.f};
    const unsigned short* fsu = (const unsigned short*)fs;
    for (int i = s0; i < s1; i++) {
        int sid = ssrc[i];
        float4 ev = *(const float4*)&el[(size_t)sid * 4];
        float e0 = ev.x + erv.x; e0 = (e0 > 0.f) ? e0 : 0.2f * e0;
        float e1 = ev.y + erv.y; e1 = (e1 > 0.f) ? e1 : 0.2f * e1;
        float e2 = ev.z + erv.z; e2 = (e2 > 0.f) ? e2 : 0.2f * e2;
        float e3 = ev.w + erv.w; e3 = (e3 > 0.f) ? e3 : 0.2f * e3;
        float a4[4] = {__expf(e0 - m0), __expf(e1 - m1), __expf(e2 - m2), __expf(e3 - m3)};
        sh[0] += a4[0]; sh[1] += a4[1]; sh[2] += a4[2]; sh[3] += a4[3];
        ushort4 f = {0, 0, 0, 0};
        if (act) f = *(const ushort4*)&fsu[(size_t)sid * HD + 4 * lane];
        unsigned short fa[4] = {f.x, f.y, f.z, f.w};
#pragma unroll
        for (int j = 0; j < 4; j++)
            acc[j] += a4[h_[j]] * bf2f(fa[j]);
    }
    if (act) {
#pragma unroll
        for (int j = 0; j < 4; j++) {
            int e4 = 4 * lane + j;
            float sv = sh[h_[j]];
            float o = (sv > 0.f) ? acc[j] / sv : 0.f;
            rst[(size_t)n * HD + e4] = __float2bfloat16(o + b[e4]);
        }
    }
}

// ---------------- final layer ----------------
__global__ void final_kernel(const bf16* __restrict__ rst2, const bf16* __restrict__ h2,
                             const float* __restrict__ Ws, const float* __restrict__ bs,
                             float* __restrict__ out)
{
    const int K = 256, C = 47;
    int n = blockIdx.x;
    int c = threadIdx.x;
    float v = -INFINITY;
    if (c < C) {
        float dot = 0.f;
        for (int k = 0; k < K; k++) dot += __bfloat162float(h2[(size_t)n * K + k]) * Ws[k * C + c];
        float mean = 0.f;
#pragma unroll
        for (int hh = 0; hh < HEADS; hh++) mean += __bfloat162float(rst2[(size_t)n * HEADS * C + hh * C + c]);
        mean *= 0.25f;
        v = mean + dot + bs[c];
    }
    float mx = v;
    for (int off = 32; off; off >>= 1) mx = fmaxf(mx, __shfl_xor(mx, off));
    float ex = (c < C) ? __expf(v - mx) : 0.f;
    float sum = ex;
    for (int off = 32; off; off >>= 1) sum += __shfl_xor(sum, off);
    if (c < C) out[n * C + c] = v - mx - logf(sum);
}

extern "C" void kernel_launch(void* const* d_in, const int* in_sizes, int n_in,
                              void* d_out, int out_size, void* d_ws, size_t ws_size,
                              hipStream_t stream)
{
    const float* x = (const float*)d_in[0];
    const float* W[3]  = {(const float*)d_in[1],  (const float*)d_in[7],  (const float*)d_in[13]};
    const float* al[3] = {(const float*)d_in[2],  (const float*)d_in[8],  (const float*)d_in[14]};
    const float* ar[3] = {(const float*)d_in[3],  (const float*)d_in[9],  (const float*)d_in[15]};
    const float* bb[3] = {(const float*)d_in[4],  (const float*)d_in[10], (const float*)d_in[16]};
    const float* Ws[3] = {(const float*)d_in[5],  (const float*)d_in[11], (const float*)d_in[17]};
    const float* bs[3] = {(const float*)d_in[6],  (const float*)d_in[12], (const float*)d_in[18]};
    const int* srcp[3] = {(const int*)d_in[19], (const int*)d_in[21], (const int*)d_in[23]};
    const int* dstp[3] = {(const int*)d_in[20], (const int*)d_in[22], (const int*)d_in[24]};

    char* p = (char*)d_ws;
    auto alloc = [&](size_t bytes) -> void* {
        void* r = (void*)p;
        p += (bytes + 255) & ~(size_t)255;
        return r;
    };
    // padded to 128-row multiples so GEMM staging never bounds-checks
    bf16*  xb    = (bf16*)alloc((size_t)200064 * 128 * 2);
    bf16*  fsb   = (bf16*)alloc((size_t)200000 * 256 * 2);
    bf16*  h1b   = (bf16*)alloc((size_t)50048 * 256 * 2);
    bf16*  h2b   = (bf16*)alloc((size_t)10112 * 256 * 2);
    bf16*  rstb  = (bf16*)alloc((size_t)50000 * 256 * 2);
    float* elb   = (float*)alloc((size_t)200000 * 4 * 4);
    float* erb   = (float*)alloc((size_t)50000 * 4 * 4);
    bf16* Wt[3]; bf16* Wst[2];
    Wt[0]  = (bf16*)alloc(256 * 128 * 2);
    Wt[1]  = (bf16*)alloc(256 * 256 * 2);
    Wt[2]  = (bf16*)alloc(256 * 256 * 2);   // padded 188->256 cols
    Wst[0] = (bf16*)alloc(256 * 128 * 2);
    Wst[1] = (bf16*)alloc(256 * 256 * 2);
    int* counts   = (int*)alloc(62048 * 4);
    int* offs_all = (int*)alloc(62051 * 4);
    int* cursor   = (int*)alloc(62048 * 4);
    int* ssrc_all = (int*)alloc(1300000 * 4);
    int* bsum     = (int*)alloc(768 * 4);
    int* bpre     = (int*)alloc(768 * 4);

    const int OOFF[3] = {0, 50001, 60002};
    const int SOFF[3] = {0, 800000, 1200000};

    // casts: 5 weight transposes + x, one dispatch
    precast_all<<<dim3(512, 6), 256, 0, stream>>>(W[0], W[1], W[2], Ws[0], Ws[1], x,
                                                  Wt[0], Wt[1], Wt[2], Wst[0], Wst[1], xb);

    // CSR for all 3 layers
    hipMemsetAsync(counts, 0, 62048 * 4, stream);
    hist3_kernel<<<512, 256, 0, stream>>>(dstp[0], dstp[1], dstp[2], counts);
    scan_a3_kernel<<<dim3(196, 3), 256, 0, stream>>>(counts, bsum);
    scan_b3_kernel<<<1, 256, 0, stream>>>(bsum, bpre, offs_all);
    scan_c3_kernel<<<dim3(196, 3), 256, 0, stream>>>(counts, bpre, offs_all, cursor);
    scatter3_kernel<<<512, 256, 0, stream>>>(srcp[0], dstp[0], srcp[1], dstp[1], srcp[2], dstp[2],
                                             cursor, ssrc_all);

    // ---- layer 0 (D=64, cin=128) ----
    gemm_mfma<0, 1><<<dim3(2, 1563), 256, 0, stream>>>(
        xb, Wt[0], nullptr, nullptr, al[0], ar[0], elb, erb, fsb, 200000, 256, 128, 50000);
    attn_agg64<<<12500, 256, 0, stream>>>(fsb, elb, erb, bb[0], offs_all + OOFF[0], ssrc_all + SOFF[0], rstb, 50000);
    gemm_mfma<1, 0><<<dim3(2, 391), 256, 0, stream>>>(
        xb, Wst[0], rstb, bs[0], nullptr, nullptr, nullptr, nullptr, h1b, 50000, 256, 128, 0);

    // ---- layer 1 (D=64, cin=256) ----
    gemm_mfma<0, 1><<<dim3(2, 391), 256, 0, stream>>>(
        h1b, Wt[1], nullptr, nullptr, al[1], ar[1], elb, erb, fsb, 50000, 256, 256, 10000);
    attn_agg64<<<2500, 256, 0, stream>>>(fsb, elb, erb, bb[1], offs_all + OOFF[1], ssrc_all + SOFF[1], rstb, 10000);
    gemm_mfma<1, 0><<<dim3(2, 79), 256, 0, stream>>>(
        h1b, Wst[1], rstb, bs[1], nullptr, nullptr, nullptr, nullptr, h2b, 10000, 256, 256, 0);

    // ---- layer 2 (D=47, cin=256) ----
    gemm_mfma<0, 0><<<dim3(2, 79), 256, 0, stream>>>(
        h2b, Wt[2], nullptr, nullptr, nullptr, nullptr, nullptr, nullptr, fsb, 10000, 188, 256, 0);
    el_er_kernel<<<10000, 256, 0, stream>>>(fsb, al[2], ar[2], elb, erb, 2048, 47);
    attn_agg_gen<<<512, 256, 0, stream>>>(fsb, elb, erb, bb[2], offs_all + OOFF[2], ssrc_all + SOFF[2], rstb, 47, 2048);
    final_kernel<<<2048, 64, 0, stream>>>(rstb, h2b, Ws[2], bs[2], (float*)d_out);
}

// Round 8
// 691.450 us; speedup vs baseline: 2.4870x; 1.0181x over previous
//
#include <hip/hip_runtime.h>
#include <hip/hip_bf16.h>
#include <cmath>

#define HEADS 4
typedef __hip_bfloat16 bf16;
typedef short short8 __attribute__((ext_vector_type(8)));
typedef unsigned short us8 __attribute__((ext_vector_type(8)));
typedef float floatx4 __attribute__((ext_vector_type(4)));
typedef unsigned int u32;

__device__ inline float bf2f(unsigned short u) {
    union { unsigned u; float f; } c; c.u = ((unsigned)u) << 16; return c.f;
}
__device__ inline short f2bs(float f) {
    bf16 h = __float2bfloat16(f);
    return *reinterpret_cast<short*>(&h);
}

// async 16B global->LDS (DMA, no VGPR round-trip). LDS dest: wave-uniform base + lane*16.
__device__ __forceinline__ void ld_lds16(const void* g, void* l) {
    __builtin_amdgcn_global_load_lds((const __attribute__((address_space(1))) u32*)g,
                                     (__attribute__((address_space(3))) u32*)l, 16, 0, 0);
}

// ---- problem constants ----
__device__ const int g_ND[3]   = {50000, 10000, 2048};
__device__ const int g_COFF[3] = {0, 50000, 60000};
__device__ const int g_OOFF[3] = {0, 50001, 60002};
__device__ const int g_NB[3]   = {196, 40, 8};

// ---------------- weights transpose-cast (5 slabs) + x cast, one dispatch ----------------
__global__ void precast_all(const float* __restrict__ W0, const float* __restrict__ W1,
                            const float* __restrict__ W2, const float* __restrict__ W3,
                            const float* __restrict__ W4, const float* __restrict__ x,
                            bf16* __restrict__ B0, bf16* __restrict__ B1, bf16* __restrict__ B2,
                            bf16* __restrict__ B3, bf16* __restrict__ B4, bf16* __restrict__ xb)
{
    int y = blockIdx.y;
    if (y == 5) {
        const float4* in = (const float4*)x;
        ushort4* out = (ushort4*)xb;
        const int n4 = 200000 * 128 / 4;
        for (int i = blockIdx.x * blockDim.x + threadIdx.x; i < n4; i += gridDim.x * blockDim.x) {
            float4 v = in[i];
            ushort4 o;
            o.x = (unsigned short)f2bs(v.x); o.y = (unsigned short)f2bs(v.y);
            o.z = (unsigned short)f2bs(v.z); o.w = (unsigned short)f2bs(v.w);
            out[i] = o;
        }
        return;
    }
    const int Ks[5] = {128, 256, 256, 128, 256};
    const int Ns[5] = {256, 256, 188, 256, 256};
    const float* W = (y == 0) ? W0 : (y == 1) ? W1 : (y == 2) ? W2 : (y == 3) ? W3 : W4;
    bf16* B = (y == 0) ? B0 : (y == 1) ? B1 : (y == 2) ? B2 : (y == 3) ? B3 : B4;
    int K = Ks[y], N = Ns[y], sz = K * N;
    for (int i = blockIdx.x * blockDim.x + threadIdx.x; i < sz; i += gridDim.x * blockDim.x) {
        int n = i / K, k = i % K;
        B[i] = __float2bfloat16(W[(size_t)k * N + n]);
    }
}

// ---------------- MFMA GEMM: C[M,N] = A[M,K] @ Bt[N,K]^T (all bf16 inputs) ----------------
template<int FUSE, int EL>
__global__ __launch_bounds__(256)
void gemm_mfma(const bf16* __restrict__ A, const bf16* __restrict__ Bt,
               const bf16* __restrict__ add, const float* __restrict__ bias,
               const float* __restrict__ al, const float* __restrict__ ar,
               float* __restrict__ el, float* __restrict__ er,
               bf16* __restrict__ Cb, int M, int N, int K, int nd)
{
    const int BM = 128, BN = 128, BK = 32;
    __shared__ short As[BM * BK];
    __shared__ short Bs[BN * BK];
    int tid = threadIdx.x;
    int wave = tid >> 6, lane = tid & 63;
    int q = lane >> 4, r = lane & 15;
    int row0 = blockIdx.y * BM, col0 = blockIdx.x * BN;
    int wm = (wave >> 1) * 64, wn = (wave & 1) * 64;

    const short* A16 = (const short*)A;
    const short* B16 = (const short*)Bt;
    const short* ga0 = A16 + (size_t)(row0 + (tid >> 2)) * K + (tid & 3) * 8;
    const short* ga1 = ga0 + (size_t)64 * K;
    const short* gb0 = B16 + (size_t)(col0 + (tid >> 2)) * K + (tid & 3) * 8;
    const short* gb1 = gb0 + (size_t)64 * K;
    char* la0 = (char*)As + tid * 16;
    char* la1 = la0 + 4096;
    char* lb0 = (char*)Bs + tid * 16;
    char* lb1 = lb0 + 4096;

    floatx4 zero = {0.f, 0.f, 0.f, 0.f};
    floatx4 acc[4][4];
#pragma unroll
    for (int i = 0; i < 4; i++)
#pragma unroll
        for (int j = 0; j < 4; j++) acc[i][j] = zero;

    for (int k0 = 0; k0 < K; k0 += BK) {
        ld_lds16(ga0, la0); ld_lds16(ga1, la1);
        ld_lds16(gb0, lb0); ld_lds16(gb1, lb1);
        ga0 += BK; ga1 += BK; gb0 += BK; gb1 += BK;
        __syncthreads();
        short8 af[4], bfr[4];
#pragma unroll
        for (int mt = 0; mt < 4; mt++) af[mt] = *(short8*)&As[(wm + mt * 16 + r) * BK + q * 8];
#pragma unroll
        for (int nt = 0; nt < 4; nt++) bfr[nt] = *(short8*)&Bs[(wn + nt * 16 + r) * BK + q * 8];
#pragma unroll
        for (int mt = 0; mt < 4; mt++)
#pragma unroll
            for (int nt = 0; nt < 4; nt++)
                acc[mt][nt] = __builtin_amdgcn_mfma_f32_16x16x32_bf16(af[mt], bfr[nt], acc[mt][nt], 0, 0, 0);
        __syncthreads();
    }

#pragma unroll
    for (int mt = 0; mt < 4; mt++) {
#pragma unroll
        for (int nt = 0; nt < 4; nt++) {
            int gcol = col0 + wn + nt * 16 + r;
            if (gcol >= N) continue;
#pragma unroll
            for (int e = 0; e < 4; e++) {
                int grow = row0 + wm + mt * 16 + q * 4 + e;
                if (grow >= M) continue;
                float v = acc[mt][nt][e];
                size_t idx = (size_t)grow * N + gcol;
                if (FUSE == 1) {
                    v += __bfloat162float(add[idx]) + bias[gcol];
                    v = (v > 0.f) ? v : (__expf(v) - 1.f);
                }
                Cb[idx] = __float2bfloat16(v);
            }
        }
    }

    if (EL) {
        int head = (col0 + wn) >> 6;
        float alh[4], arh[4];
#pragma unroll
        for (int nt = 0; nt < 4; nt++) {
            int c = nt * 16 + r;
            alh[nt] = al[head * 64 + c];
            arh[nt] = ar[head * 64 + c];
        }
#pragma unroll
        for (int mt = 0; mt < 4; mt++) {
#pragma unroll
            for (int e = 0; e < 4; e++) {
                float pl = 0.f, pr = 0.f;
#pragma unroll
                for (int nt = 0; nt < 4; nt++) {
                    float v = acc[mt][nt][e];
                    pl += v * alh[nt];
                    pr += v * arh[nt];
                }
#pragma unroll
                for (int off = 1; off < 16; off <<= 1) {
                    pl += __shfl_xor(pl, off);
                    pr += __shfl_xor(pr, off);
                }
                int grow = row0 + wm + mt * 16 + q * 4 + e;
                if (r == 0 && grow < M) {
                    el[grow * 4 + head] = pl;
                    if (grow < nd) er[grow * 4 + head] = pr;
                }
            }
        }
    }
}

// ---------------- el/er generic (layer 2, D=47) ----------------
__global__ void el_er_kernel(const bf16* __restrict__ fs, const float* __restrict__ al,
                             const float* __restrict__ ar, float* __restrict__ el,
                             float* __restrict__ er, int nd, int D)
{
    int n = blockIdx.x;
    int h = threadIdx.x >> 6;
    int d = threadIdx.x & 63;
    int HD = HEADS * D;
    float v = 0.f, a = 0.f, rr = 0.f;
    if (d < D) {
        v = __bfloat162float(fs[(size_t)n * HD + h * D + d]);
        a = al[h * D + d];
        rr = ar[h * D + d];
    }
    float pl = v * a, pr = v * rr;
    for (int off = 32; off; off >>= 1) {
        pl += __shfl_down(pl, off);
        pr += __shfl_down(pr, off);
    }
    if (d == 0) {
        el[n * HEADS + h] = pl;
        if (n < nd) er[n * HEADS + h] = pr;
    }
}

// ---------------- CSR build: 1 thread per edge (max MLP for atomics) ----------------
__global__ void hist3_kernel(const int* __restrict__ d0, const int* __restrict__ d1,
                             const int* __restrict__ d2, int* __restrict__ cnt)
{
    int i = blockIdx.x * blockDim.x + threadIdx.x;
    if (i >= 1300000) return;
    int base, d;
    if (i < 800000)       { base = 0;     d = d0[i]; }
    else if (i < 1200000) { base = 50000; d = d1[i - 800000]; }
    else                  { base = 60000; d = d2[i - 1200000]; }
    atomicAdd(&cnt[base + d], 1);
}

__global__ void scan_a3_kernel(const int* __restrict__ cnt, int* __restrict__ bsum)
{
    __shared__ int sdata[256];
    int l = blockIdx.y;
    if ((int)blockIdx.x >= g_NB[l]) return;
    int nd = g_ND[l], coff = g_COFF[l];
    int i = blockIdx.x * 256 + threadIdx.x;
    sdata[threadIdx.x] = (i < nd) ? cnt[coff + i] : 0;
    __syncthreads();
    for (int off = 128; off; off >>= 1) {
        if (threadIdx.x < off) sdata[threadIdx.x] += sdata[threadIdx.x + off];
        __syncthreads();
    }
    if (threadIdx.x == 0) bsum[l * 256 + blockIdx.x] = sdata[0];
}

__global__ void scan_b3_kernel(const int* __restrict__ bsum, int* __restrict__ bpre,
                               int* __restrict__ offs)
{
    __shared__ int sdata[256];
    int tid = threadIdx.x;
    for (int l = 0; l < 3; l++) {
        int v = (tid < g_NB[l]) ? bsum[l * 256 + tid] : 0;
        sdata[tid] = v;
        __syncthreads();
        for (int off = 1; off < 256; off <<= 1) {
            int t = (tid >= off) ? sdata[tid - off] : 0;
            __syncthreads();
            sdata[tid] += t;
            __syncthreads();
        }
        bpre[l * 256 + tid] = sdata[tid] - v;
        if (tid == 255) offs[g_OOFF[l] + g_ND[l]] = sdata[255];
        __syncthreads();
    }
}

__global__ void scan_c3_kernel(const int* __restrict__ cnt, const int* __restrict__ bpre,
                               int* __restrict__ offs, int* __restrict__ cursor)
{
    __shared__ int sdata[256];
    int l = blockIdx.y;
    if ((int)blockIdx.x >= g_NB[l]) return;
    int nd = g_ND[l], coff = g_COFF[l], ooff = g_OOFF[l];
    int tid = threadIdx.x;
    int i = blockIdx.x * 256 + tid;
    int v = (i < nd) ? cnt[coff + i] : 0;
    sdata[tid] = v;
    __syncthreads();
    for (int off = 1; off < 256; off <<= 1) {
        int t = (tid >= off) ? sdata[tid - off] : 0;
        __syncthreads();
        sdata[tid] += t;
        __syncthreads();
    }
    if (i < nd) {
        int e = bpre[l * 256 + blockIdx.x] + sdata[tid] - v;
        offs[ooff + i] = e;
        cursor[coff + i] = e;
    }
}

__global__ void scatter3_kernel(const int* __restrict__ s0, const int* __restrict__ d0,
                                const int* __restrict__ s1, const int* __restrict__ d1,
                                const int* __restrict__ s2, const int* __restrict__ d2,
                                int* __restrict__ cursor, int* __restrict__ ssrc)
{
    int i = blockIdx.x * blockDim.x + threadIdx.x;
    if (i >= 1300000) return;
    int base, soff, sv, dv;
    if (i < 800000)       { base = 0;     soff = 0;       sv = s0[i];           dv = d0[i]; }
    else if (i < 1200000) { base = 50000; soff = 800000;  sv = s1[i - 800000];  dv = d1[i - 800000]; }
    else                  { base = 60000; soff = 1200000; sv = s2[i - 1200000]; dv = d2[i - 1200000]; }
    int p = atomicAdd(&cursor[base + dv], 1);
    ssrc[soff + p] = sv;
}

// ---------------- fused attention+aggregation, D=64 (HD=256) ----------------
__global__ __launch_bounds__(256)
void attn_agg64(const bf16* __restrict__ fs, const float* __restrict__ el,
                const float* __restrict__ er, const float* __restrict__ b,
                const int* __restrict__ offs, const int* __restrict__ ssrc,
                bf16* __restrict__ rst, int nd)
{
    int wave = threadIdx.x >> 6, lane = threadIdx.x & 63;
    int n = blockIdx.x * 4 + wave;
    if (n >= nd) return;
    int s0 = offs[n], s1 = offs[n + 1];
    float4 erv = *(const float4*)&er[(size_t)n * 4];

    float m0 = -INFINITY, m1 = -INFINITY, m2 = -INFINITY, m3 = -INFINITY;
    for (int i = s0 + lane; i < s1; i += 64) {
        int sid = ssrc[i];
        float4 ev = *(const float4*)&el[(size_t)sid * 4];
        float e0 = ev.x + erv.x; e0 = (e0 > 0.f) ? e0 : 0.2f * e0;
        float e1 = ev.y + erv.y; e1 = (e1 > 0.f) ? e1 : 0.2f * e1;
        float e2 = ev.z + erv.z; e2 = (e2 > 0.f) ? e2 : 0.2f * e2;
        float e3 = ev.w + erv.w; e3 = (e3 > 0.f) ? e3 : 0.2f * e3;
        m0 = fmaxf(m0, e0); m1 = fmaxf(m1, e1); m2 = fmaxf(m2, e2); m3 = fmaxf(m3, e3);
    }
#pragma unroll
    for (int off = 32; off; off >>= 1) {
        m0 = fmaxf(m0, __shfl_xor(m0, off));
        m1 = fmaxf(m1, __shfl_xor(m1, off));
        m2 = fmaxf(m2, __shfl_xor(m2, off));
        m3 = fmaxf(m3, __shfl_xor(m3, off));
    }

    int half = lane >> 5, sub = lane & 31, head = sub >> 3;
    float mh  = (head == 0) ? m0 : (head == 1) ? m1 : (head == 2) ? m2 : m3;
    float eh  = (head == 0) ? erv.x : (head == 1) ? erv.y : (head == 2) ? erv.z : erv.w;
    const unsigned short* fsu = (const unsigned short*)fs;

    float acc[8];
#pragma unroll
    for (int j = 0; j < 8; j++) acc[j] = 0.f;
    float s = 0.f;

    int cnt = s1 - s0;
    int npairs = cnt >> 1;
    int i = s0 + half;
    if (npairs > 0) {
        int sid = ssrc[i];
        float ev = el[(size_t)sid * 4 + head];
        us8 f = *(const us8*)&fsu[(size_t)sid * 256 + sub * 8];
        for (int p = 1; p < npairs; p++) {
            i += 2;
            int sid2 = ssrc[i];
            float ev2 = el[(size_t)sid2 * 4 + head];
            us8 f2 = *(const us8*)&fsu[(size_t)sid2 * 256 + sub * 8];
            float e = ev + eh; e = (e > 0.f) ? e : 0.2f * e;
            float a = __expf(e - mh);
            s += a;
#pragma unroll
            for (int j = 0; j < 8; j++) acc[j] += a * bf2f(f[j]);
            ev = ev2; f = f2;
        }
        float e = ev + eh; e = (e > 0.f) ? e : 0.2f * e;
        float a = __expf(e - mh);
        s += a;
#pragma unroll
        for (int j = 0; j < 8; j++) acc[j] += a * bf2f(f[j]);
    }
    if (cnt & 1) {
        int idx = s1 - 1;
        int sid = ssrc[idx];
        float ev = el[(size_t)sid * 4 + head];
        us8 f = *(const us8*)&fsu[(size_t)sid * 256 + sub * 8];
        float e = ev + eh; e = (e > 0.f) ? e : 0.2f * e;
        float a = __expf(e - mh);
        if (half) a = 0.f;
        s += a;
#pragma unroll
        for (int j = 0; j < 8; j++) acc[j] += a * bf2f(f[j]);
    }
    s += __shfl_xor(s, 32);
#pragma unroll
    for (int j = 0; j < 8; j++) acc[j] += __shfl_xor(acc[j], 32);
    if (half == 0) {
        float inv = (s > 0.f) ? 1.f / s : 0.f;
        float4 b0 = *(const float4*)&b[sub * 8];
        float4 b1 = *(const float4*)&b[sub * 8 + 4];
        us8 o;
        o[0] = (unsigned short)f2bs(acc[0] * inv + b0.x);
        o[1] = (unsigned short)f2bs(acc[1] * inv + b0.y);
        o[2] = (unsigned short)f2bs(acc[2] * inv + b0.z);
        o[3] = (unsigned short)f2bs(acc[3] * inv + b0.w);
        o[4] = (unsigned short)f2bs(acc[4] * inv + b1.x);
        o[5] = (unsigned short)f2bs(acc[5] * inv + b1.y);
        o[6] = (unsigned short)f2bs(acc[6] * inv + b1.z);
        o[7] = (unsigned short)f2bs(acc[7] * inv + b1.w);
        *(us8*)&((unsigned short*)rst)[(size_t)n * 256 + sub * 8] = o;
    }
}

// ---------------- fused attention+aggregation generic (layer 2, D=47) ----------------
__global__ void attn_agg_gen(const bf16* __restrict__ fs, const float* __restrict__ el,
                             const float* __restrict__ er, const float* __restrict__ b,
                             const int* __restrict__ offs, const int* __restrict__ ssrc,
                             bf16* __restrict__ rst, int D, int nd)
{
    int wave = threadIdx.x >> 6, lane = threadIdx.x & 63;
    int n = blockIdx.x * 4 + wave;
    if (n >= nd) return;
    int HD = HEADS * D;
    int s0 = offs[n], s1 = offs[n + 1];
    float4 erv = *(const float4*)&er[(size_t)n * 4];

    float m0 = -INFINITY, m1 = -INFINITY, m2 = -INFINITY, m3 = -INFINITY;
    for (int i = s0 + lane; i < s1; i += 64) {
        int sid = ssrc[i];
        float4 ev = *(const float4*)&el[(size_t)sid * 4];
        float e0 = ev.x + erv.x; e0 = (e0 > 0.f) ? e0 : 0.2f * e0;
        float e1 = ev.y + erv.y; e1 = (e1 > 0.f) ? e1 : 0.2f * e1;
        float e2 = ev.z + erv.z; e2 = (e2 > 0.f) ? e2 : 0.2f * e2;
        float e3 = ev.w + erv.w; e3 = (e3 > 0.f) ? e3 : 0.2f * e3;
        m0 = fmaxf(m0, e0); m1 = fmaxf(m1, e1); m2 = fmaxf(m2, e2); m3 = fmaxf(m3, e3);
    }
#pragma unroll
    for (int off = 32; off; off >>= 1) {
        m0 = fmaxf(m0, __shfl_xor(m0, off));
        m1 = fmaxf(m1, __shfl_xor(m1, off));
        m2 = fmaxf(m2, __shfl_xor(m2, off));
        m3 = fmaxf(m3, __shfl_xor(m3, off));
    }

    bool act = (4 * lane) < HD;
    int h_[4];
#pragma unroll
    for (int j = 0; j < 4; j++) {
        int e = 4 * lane + j;
        h_[j] = (e < HD) ? (e / D) : 0;
    }
    float acc[4] = {0.f, 0.f, 0.f, 0.f};
    float sh[4] = {0.f, 0.f, 0.f, 0.f};
    const unsigned short* fsu = (const unsigned short*)fs;
    for (int i = s0; i < s1; i++) {
        int sid = ssrc[i];
        float4 ev = *(const float4*)&el[(size_t)sid * 4];
        float e0 = ev.x + erv.x; e0 = (e0 > 0.f) ? e0 : 0.2f * e0;
        float e1 = ev.y + erv.y; e1 = (e1 > 0.f) ? e1 : 0.2f * e1;
        float e2 = ev.z + erv.z; e2 = (e2 > 0.f) ? e2 : 0.2f * e2;
        float e3 = ev.w + erv.w; e3 = (e3 > 0.f) ? e3 : 0.2f * e3;
        float a4[4] = {__expf(e0 - m0), __expf(e1 - m1), __expf(e2 - m2), __expf(e3 - m3)};
        sh[0] += a4[0]; sh[1] += a4[1]; sh[2] += a4[2]; sh[3] += a4[3];
        ushort4 f = {0, 0, 0, 0};
        if (act) f = *(const ushort4*)&fsu[(size_t)sid * HD + 4 * lane];
        unsigned short fa[4] = {f.x, f.y, f.z, f.w};
#pragma unroll
        for (int j = 0; j < 4; j++)
            acc[j] += a4[h_[j]] * bf2f(fa[j]);
    }
    if (act) {
#pragma unroll
        for (int j = 0; j < 4; j++) {
            int e4 = 4 * lane + j;
            float sv = sh[h_[j]];
            float o = (sv > 0.f) ? acc[j] / sv : 0.f;
            rst[(size_t)n * HD + e4] = __float2bfloat16(o + b[e4]);
        }
    }
}

// ---------------- final layer ----------------
__global__ void final_kernel(const bf16* __restrict__ rst2, const bf16* __restrict__ h2,
                             const float* __restrict__ Ws, const float* __restrict__ bs,
                             float* __restrict__ out)
{
    const int K = 256, C = 47;
    int n = blockIdx.x;
    int c = threadIdx.x;
    float v = -INFINITY;
    if (c < C) {
        float dot = 0.f;
        for (int k = 0; k < K; k++) dot += __bfloat162float(h2[(size_t)n * K + k]) * Ws[k * C + c];
        float mean = 0.f;
#pragma unroll
        for (int hh = 0; hh < HEADS; hh++) mean += __bfloat162float(rst2[(size_t)n * HEADS * C + hh * C + c]);
        mean *= 0.25f;
        v = mean + dot + bs[c];
    }
    float mx = v;
    for (int off = 32; off; off >>= 1) mx = fmaxf(mx, __shfl_xor(mx, off));
    float ex = (c < C) ? __expf(v - mx) : 0.f;
    float sum = ex;
    for (int off = 32; off; off >>= 1) sum += __shfl_xor(sum, off);
    if (c < C) out[n * C + c] = v - mx - logf(sum);
}

extern "C" void kernel_launch(void* const* d_in, const int* in_sizes, int n_in,
                              void* d_out, int out_size, void* d_ws, size_t ws_size,
                              hipStream_t stream)
{
    const float* x = (const float*)d_in[0];
    const float* W[3]  = {(const float*)d_in[1],  (const float*)d_in[7],  (const float*)d_in[13]};
    const float* al[3] = {(const float*)d_in[2],  (const float*)d_in[8],  (const float*)d_in[14]};
    const float* ar[3] = {(const float*)d_in[3],  (const float*)d_in[9],  (const float*)d_in[15]};
    const float* bb[3] = {(const float*)d_in[4],  (const float*)d_in[10], (const float*)d_in[16]};
    const float* Ws[3] = {(const float*)d_in[5],  (const float*)d_in[11], (const float*)d_in[17]};
    const float* bs[3] = {(const float*)d_in[6],  (const float*)d_in[12], (const float*)d_in[18]};
    const int* srcp[3] = {(const int*)d_in[19], (const int*)d_in[21], (const int*)d_in[23]};
    const int* dstp[3] = {(const int*)d_in[20], (const int*)d_in[22], (const int*)d_in[24]};

    char* p = (char*)d_ws;
    auto alloc = [&](size_t bytes) -> void* {
        void* r = (void*)p;
        p += (bytes + 255) & ~(size_t)255;
        return r;
    };
    bf16*  xb    = (bf16*)alloc((size_t)200064 * 128 * 2);
    bf16*  fsb   = (bf16*)alloc((size_t)200000 * 256 * 2);
    bf16*  h1b   = (bf16*)alloc((size_t)50048 * 256 * 2);
    bf16*  h2b   = (bf16*)alloc((size_t)10112 * 256 * 2);
    bf16*  rstb  = (bf16*)alloc((size_t)50000 * 256 * 2);
    float* elb   = (float*)alloc((size_t)200000 * 4 * 4);
    float* erb   = (float*)alloc((size_t)50000 * 4 * 4);
    bf16* Wt[3]; bf16* Wst[2];
    Wt[0]  = (bf16*)alloc(256 * 128 * 2);
    Wt[1]  = (bf16*)alloc(256 * 256 * 2);
    Wt[2]  = (bf16*)alloc(256 * 256 * 2);
    Wst[0] = (bf16*)alloc(256 * 128 * 2);
    Wst[1] = (bf16*)alloc(256 * 256 * 2);
    int* counts   = (int*)alloc(62048 * 4);
    int* offs_all = (int*)alloc(62051 * 4);
    int* cursor   = (int*)alloc(62048 * 4);
    int* ssrc_all = (int*)alloc(1300000 * 4);
    int* bsum     = (int*)alloc(768 * 4);
    int* bpre     = (int*)alloc(768 * 4);

    const int OOFF[3] = {0, 50001, 60002};
    const int SOFF[3] = {0, 800000, 1200000};
    const int EB = (1300000 + 255) / 256;   // one thread per edge

    precast_all<<<dim3(512, 6), 256, 0, stream>>>(W[0], W[1], W[2], Ws[0], Ws[1], x,
                                                  Wt[0], Wt[1], Wt[2], Wst[0], Wst[1], xb);

    hipMemsetAsync(counts, 0, 62048 * 4, stream);
    hist3_kernel<<<EB, 256, 0, stream>>>(dstp[0], dstp[1], dstp[2], counts);
    scan_a3_kernel<<<dim3(196, 3), 256, 0, stream>>>(counts, bsum);
    scan_b3_kernel<<<1, 256, 0, stream>>>(bsum, bpre, offs_all);
    scan_c3_kernel<<<dim3(196, 3), 256, 0, stream>>>(counts, bpre, offs_all, cursor);
    scatter3_kernel<<<EB, 256, 0, stream>>>(srcp[0], dstp[0], srcp[1], dstp[1], srcp[2], dstp[2],
                                            cursor, ssrc_all);

    // ---- layer 0 (D=64, cin=128) ----
    gemm_mfma<0, 1><<<dim3(2, 1563), 256, 0, stream>>>(
        xb, Wt[0], nullptr, nullptr, al[0], ar[0], elb, erb, fsb, 200000, 256, 128, 50000);
    attn_agg64<<<12500, 256, 0, stream>>>(fsb, elb, erb, bb[0], offs_all + OOFF[0], ssrc_all + SOFF[0], rstb, 50000);
    gemm_mfma<1, 0><<<dim3(2, 391), 256, 0, stream>>>(
        xb, Wst[0], rstb, bs[0], nullptr, nullptr, nullptr, nullptr, h1b, 50000, 256, 128, 0);

    // ---- layer 1 (D=64, cin=256) ----
    gemm_mfma<0, 1><<<dim3(2, 391), 256, 0, stream>>>(
        h1b, Wt[1], nullptr, nullptr, al[1], ar[1], elb, erb, fsb, 50000, 256, 256, 10000);
    attn_agg64<<<2500, 256, 0, stream>>>(fsb, elb, erb, bb[1], offs_all + OOFF[1], ssrc_all + SOFF[1], rstb, 10000);
    gemm_mfma<1, 0><<<dim3(2, 79), 256, 0, stream>>>(
        h1b, Wst[1], rstb, bs[1], nullptr, nullptr, nullptr, nullptr, h2b, 10000, 256, 256, 0);

    // ---- layer 2 (D=47, cin=256) ----
    gemm_mfma<0, 0><<<dim3(2, 79), 256, 0, stream>>>(
        h2b, Wt[2], nullptr, nullptr, nullptr, nullptr, nullptr, nullptr, fsb, 10000, 188, 256, 0);
    el_er_kernel<<<10000, 256, 0, stream>>>(fsb, al[2], ar[2], elb, erb, 2048, 47);
    attn_agg_gen<<<512, 256, 0, stream>>>(fsb, elb, erb, bb[2], offs_all + OOFF[2], ssrc_all + SOFF[2], rstb, 47, 2048);
    final_kernel<<<2048, 64, 0, stream>>>(rstb, h2b, Ws[2], bs[2], (float*)d_out);
}